// Round 7
// baseline (142.242 us; speedup 1.0000x reference)
//
#include <hip/hip_runtime.h>
#include <math.h>

// ---------------------------------------------------------------------------
// Problem: B=4, N=2048, D=256.
// Key exact simplifications:
//  * intra+inter == 1  -> attention = softmax_j(leaky_relu(s1_i + s2_j)), no masks
//  * rank-1 + monotone -> h_prime via sorted-s2 prefix sums (O(N D), exact)
//  * evt / k_base / w_i / w_o folded into matvecs; only 3 big GEMMs remain
// R1: k_hprime -> k_rank + k_hprime2 (was 73us latency-bound).
// R2: k_setup -> k_qpart + k_qfinish + k_rowdots (was 64us, 4 blocks).
// R3: f32 VALU GEMMs -> bf16 MFMA 16x16x32 (3x40us -> ~8us each).
// R4: k_logits fused into k_hprime2; k_p2 folded into k_p3; tail GEMMs merged.
// R5: rank-by-count as k_cnt2 (split-k, 512 blocks) + k_cntfin.
// R6: u.wq dots folded into k_u (hprime2 stops reading UE/UA, -32MB);
//     softmax+final+tail-GEMMs fused into k_mgemm2f (BM=32,BN=256, 8 waves,
//     both measures in one k-loop, epilogue writes out+probs; VE/VA never
//     materialized, -32MB); k_bt+k_qpart merged. 17 -> 15 dispatches.
// ---------------------------------------------------------------------------

namespace {
constexpr int B = 4, N = 2048, D = 256;
constexpr float ALPHA = 0.2f;
constexpr float INVS  = 0.0625f;   // 1/sqrt(256)

// ws offsets (float elements)
constexpr size_t OFF_H     = 0;                       // (B,N,D)
constexpr size_t OFF_HP    = 2097152;                 // h_prime
constexpr size_t OFF_UE    = 4194304;                 // u_emo
constexpr size_t OFF_UA    = 6291456;                 // u_act
constexpr size_t OFF_PPOS  = 8388608;                 // (B,N+1,D) prefix
constexpr size_t OFF_PNEG  = 10486784;                // (B,N+1,D) prefix
constexpr size_t OFF_S1    = 12584960;                // (B,N)
constexpr size_t OFF_S2    = OFF_S1 + 8192;
constexpr size_t OFF_SV    = OFF_S2 + 8192;           // sorted s2
constexpr size_t OFF_SIDX  = OFF_SV + 8192;           // permutation (int)
constexpr size_t OFF_WP    = OFF_SIDX + 8192;         // e^{s2} sorted
constexpr size_t OFF_WN    = OFF_WP + 8192;           // e^{a s2} sorted
constexpr size_t OFF_ZP    = OFF_WN + 8192;           // (B,N+1) scalar prefix
constexpr size_t OFF_ZN    = OFF_ZP + 8196;
constexpr size_t OFF_PARTP = OFF_ZN + 8196;           // (B,32,D) chunk partials
constexpr size_t OFF_PARTN = OFF_PARTP + 32768;
constexpr size_t OFF_LE    = OFF_PARTN + 32768;       // emo logits
constexpr size_t OFF_LA    = OFF_LE + 8192;           // act logits
constexpr size_t OFF_SET   = OFF_LA + 8192;
constexpr size_t KQE = OFF_SET + 0;      // kW@q per batch (B,256)
constexpr size_t WQE = OFF_SET + 1024;
constexpr size_t KQA = OFF_SET + 2048;
constexpr size_t WQA = OFF_SET + 3072;
constexpr size_t QCE = OFF_SET + 4096;   // q + vb + wb
constexpr size_t QCA = OFF_SET + 5120;
constexpr size_t CA2 = OFF_SET + 6144;   // csk_W @ a2 (256)
constexpr size_t CEc = OFF_SET + 6400;   // q.(kb+wb) per batch
constexpr size_t CAc = OFF_SET + 6404;
constexpr size_t C2c = OFF_SET + 6408;   // 2*csk_b.a2
constexpr size_t OFF_RNK   = OFF_SET + 8192;          // (B,N) int
constexpr size_t OFF_C0    = OFF_RNK + 8192;          // ep/den
constexpr size_t OFF_C1    = OFF_C0 + 8192;           // en/den
constexpr size_t OFF_PARTQ = OFF_C1 + 8192;           // [m2][c16][b4][256]
constexpr size_t OFF_QE    = OFF_PARTQ + 32768;       // (B,256)
constexpr size_t OFF_QA    = OFF_QE + 1024;
constexpr size_t OFF_BT    = OFF_QA + 1024;           // 5 x 256x256 bf16 (ushort)
constexpr size_t OFF_PCNT  = OFF_BT + 163840;         // (B,16,N) int partials
// R6:
constexpr size_t OFF_LEU   = OFF_PCNT + 131072;       // u.wq dots (B,N)
constexpr size_t OFF_LAU   = OFF_LEU + 8192;
constexpr size_t SMXE      = OFF_LAU + 8192;          // softmax max/inv (B each)
constexpr size_t SIVE      = SMXE + 4;
constexpr size_t SMXA      = SIVE + 4;
constexpr size_t SIVA      = SMXA + 4;
}

typedef __attribute__((ext_vector_type(8))) short bf16x8;
typedef __attribute__((ext_vector_type(4))) float f32x4;

__device__ inline float wave_sum(float v) {
#pragma unroll
  for (int off = 32; off > 0; off >>= 1) v += __shfl_xor(v, off, 64);
  return v;
}

__device__ inline ushort f2bf(float x) {
  union { float f; uint u; } v; v.f = x;
  return (ushort)((v.u + 0x7FFFu + ((v.u >> 16) & 1u)) >> 16);
}
__device__ inline uint pk2bf(float a, float b) {
  return (uint)f2bf(a) | ((uint)f2bf(b) << 16);
}

// --- R6: fused weight-transpose (y<5) + q split-k partials (y>=5) -------------
__global__ __launch_bounds__(256) void k_btq(
    const float* __restrict__ Wm, const float* __restrict__ eW,
    const float* __restrict__ aW, const float* __restrict__ inp,
    const float* __restrict__ emo, const int* __restrict__ cl,
    ushort* __restrict__ bt, float* __restrict__ ws)
{
  __shared__ float smem[64*65];
  if (blockIdx.y < 5) {
    int m = blockIdx.y;
    const float* src = (m == 0) ? Wm : (m == 1) ? eW + 3*65536 : (m == 2) ? eW
                     : (m == 3) ? aW + 3*65536 : aW;
    ushort* dst = bt + (size_t)m*65536;
    int k0 = (blockIdx.x >> 2)*64, n0 = (blockIdx.x & 3)*64;
    int r = threadIdx.x >> 2, c0 = (threadIdx.x & 3)*16;
#pragma unroll
    for (int cc = 0; cc < 16; cc += 4)
      *(float4*)&smem[r*65 + c0+cc] = *(const float4*)&src[(size_t)(k0+r)*256 + n0 + c0 + cc];
    __syncthreads();
    int n = threadIdx.x >> 2, kq = (threadIdx.x & 3)*16;
    uint4 o0, o1;
    o0.x = pk2bf(smem[(kq+ 0)*65+n], smem[(kq+ 1)*65+n]);
    o0.y = pk2bf(smem[(kq+ 2)*65+n], smem[(kq+ 3)*65+n]);
    o0.z = pk2bf(smem[(kq+ 4)*65+n], smem[(kq+ 5)*65+n]);
    o0.w = pk2bf(smem[(kq+ 6)*65+n], smem[(kq+ 7)*65+n]);
    o1.x = pk2bf(smem[(kq+ 8)*65+n], smem[(kq+ 9)*65+n]);
    o1.y = pk2bf(smem[(kq+10)*65+n], smem[(kq+11)*65+n]);
    o1.z = pk2bf(smem[(kq+12)*65+n], smem[(kq+13)*65+n]);
    o1.w = pk2bf(smem[(kq+14)*65+n], smem[(kq+15)*65+n]);
    *(uint4*)&dst[(size_t)(n0+n)*256 + k0 + kq]     = o0;
    *(uint4*)&dst[(size_t)(n0+n)*256 + k0 + kq + 8] = o1;
  } else {
    int c = blockIdx.x;          // k-chunk 0..15
    int m = blockIdx.y - 5;      // 0=emo, 1=act
    int d = threadIdx.x;
    if (d < 64) {
      int b = d >> 4, kk = d & 15;
      int t = cl[b] - 1;
      size_t idx = ((size_t)b*N + t)*D + c*16 + kk;
      float v = inp[idx];
      if (m == 0) v += emo[idx];
      smem[b*16 + kk] = v;
    }
    __syncthreads();
    const float* Wq = (m ? aW : eW) + (size_t)D*D;   // lin_W[1]
    float acc0 = 0.f, acc1 = 0.f, acc2 = 0.f, acc3 = 0.f;
#pragma unroll
    for (int kk = 0; kk < 16; ++kk) {
      int k = c*16 + kk;
      float w = Wq[(size_t)k*D + d];
      acc0 += smem[0*16+kk]*w; acc1 += smem[1*16+kk]*w;
      acc2 += smem[2*16+kk]*w; acc3 += smem[3*16+kk]*w;
    }
    size_t base = OFF_PARTQ + ((size_t)(m*16 + c)*4)*256 + d;
    ws[base + 0*256] = acc0; ws[base + 1*256] = acc1;
    ws[base + 2*256] = acc2; ws[base + 3*256] = acc3;
  }
}

// --- R4: MFMA body with inline f32->bf16 A staging (h = inp @ W) --------------
__global__ __launch_bounds__(256) void k_mgemmh(
    const float* __restrict__ A1, const ushort* __restrict__ bt,
    float* __restrict__ C)
{
  __shared__ ushort As[64*40];
  const int t = threadIdx.x;
  const int lane = t & 63, w = t >> 6;
  const int wm = w >> 1, wn = w & 1;
  const int laneN = lane & 15, kg = lane >> 4;
  const int m0 = blockIdx.x * 64, n0 = blockIdx.y * 128;
  const int srow = t >> 2, sq = t & 3;
  f32x4 acc[2][4] = {};
  for (int k0 = 0; k0 < 256; k0 += 32) {
    __syncthreads();
    float4 f0 = *(const float4*)&A1[(size_t)(m0 + srow)*256 + k0 + sq*8];
    float4 f1 = *(const float4*)&A1[(size_t)(m0 + srow)*256 + k0 + sq*8 + 4];
    uint4 o;
    o.x = pk2bf(f0.x, f0.y); o.y = pk2bf(f0.z, f0.w);
    o.z = pk2bf(f1.x, f1.y); o.w = pk2bf(f1.z, f1.w);
    *(uint4*)&As[srow*40 + sq*8] = o;
    __syncthreads();
    bf16x8 bf[4];
#pragma unroll
    for (int j = 0; j < 4; ++j)
      bf[j] = *(const bf16x8*)&bt[(size_t)(n0 + wn*64 + j*16 + laneN)*256 + k0 + kg*8];
#pragma unroll
    for (int i = 0; i < 2; ++i) {
      bf16x8 af = *(const bf16x8*)&As[(wm*32 + i*16 + laneN)*40 + kg*8];
#pragma unroll
      for (int j = 0; j < 4; ++j)
        acc[i][j] = __builtin_amdgcn_mfma_f32_16x16x32_bf16(af, bf[j], acc[i][j], 0, 0, 0);
    }
  }
#pragma unroll
  for (int i = 0; i < 2; ++i)
#pragma unroll
    for (int j = 0; j < 4; ++j)
#pragma unroll
      for (int r = 0; r < 4; ++r)
        C[(size_t)(m0 + wm*32 + i*16 + kg*4 + r)*256 + n0 + wn*64 + j*16 + laneN]
            = acc[i][j][r];
}

// --- R2: q = sum partials + qb; qc; scalar dots --------------------------------
__global__ __launch_bounds__(256) void k_qfinish(
    const float* __restrict__ eb, const float* __restrict__ ab,
    const float* __restrict__ cskb, const float* __restrict__ a,
    float* __restrict__ ws)
{
  int b = blockIdx.x, m = blockIdx.y, d = threadIdx.x;
  __shared__ float red[D];
  const float* bias = m ? ab : eb;
  float q = bias[D + d];
#pragma unroll
  for (int c = 0; c < 16; ++c)
    q += ws[OFF_PARTQ + ((size_t)(m*16 + c)*4 + b)*256 + d];
  ws[(m ? OFF_QA : OFF_QE) + (size_t)b*D + d] = q;
  ws[(m ? QCA : QCE) + (size_t)b*D + d] = q + bias[3*D + d] + bias[0*D + d];
  red[d] = q * (bias[2*D + d] + bias[0*D + d]);
  __syncthreads();
  for (int s = 128; s > 0; s >>= 1) { if (d < s) red[d] += red[d+s]; __syncthreads(); }
  if (d == 0) ws[(m ? CAc : CEc) + b] = red[0];
  if (m == 1 && b == 0) {
    __syncthreads();
    red[d] = cskb[d] * a[D + d];
    __syncthreads();
    for (int s = 128; s > 0; s >>= 1) { if (d < s) red[d] += red[d+s]; __syncthreads(); }
    if (d == 0) ws[C2c] = 2.0f * red[0];
  }
}

// --- R2: 17 row-major matvecs, wave-per-row, coalesced -------------------------
__global__ __launch_bounds__(256) void k_rowdots(
    const float* __restrict__ eW, const float* __restrict__ aW,
    const float* __restrict__ cskW, const float* __restrict__ a,
    float* __restrict__ ws)
{
  int job = blockIdx.y;
  int wid = threadIdx.x >> 6, lane = threadIdx.x & 63;
  int row = blockIdx.x*4 + wid;
  __shared__ float vec[D];
  const float* M; size_t outo;
  if (job < 16) {
    int b = job >> 2, m = (job >> 1) & 1, which = job & 1;
    const float* base = m ? aW : eW;
    M = base + (which ? 0 : (size_t)2*D*D);          // wW : kW
    if (threadIdx.x < D)
      vec[threadIdx.x] = ws[(m ? OFF_QA : OFF_QE) + (size_t)b*D + threadIdx.x];
    outo = (which ? (m ? WQA : WQE) : (m ? KQA : KQE)) + (size_t)b*D;
  } else {
    M = cskW;
    if (threadIdx.x < D) vec[threadIdx.x] = a[D + threadIdx.x];
    outo = CA2;
  }
  __syncthreads();
  float4 w = *reinterpret_cast<const float4*>(&M[(size_t)row*D + lane*4]);
  float s = w.x*vec[lane*4] + w.y*vec[lane*4+1] + w.z*vec[lane*4+2] + w.w*vec[lane*4+3];
  s = wave_sum(s);
  if (lane == 0) ws[outo + row] = s;
}

// --- R6: u = select + u.wq row dots (one wave == one row) ---------------------
__global__ __launch_bounds__(256) void k_u(
    const float* __restrict__ ei, const float* __restrict__ eo,
    const float* __restrict__ ai, const float* __restrict__ ao,
    const int* __restrict__ cl, const int* __restrict__ intra,
    float* __restrict__ ws)
{
  size_t g = (size_t)blockIdx.x*256 + threadIdx.x;
  size_t base = g << 2;
  int b = (int)(base >> 19);              // N*D = 2^19
  int n = (int)((base >> 8) & (N - 1));
  int d0 = (int)(base & (D - 1));
  int t = cl[b] - 1;
  float tm = (float)intra[(size_t)b*N*N + (size_t)t*N + n];
  float om = 1.0f - tm;
  float4 vei = *(const float4*)&ei[base];
  float4 veo = *(const float4*)&eo[base];
  float4 vai = *(const float4*)&ai[base];
  float4 vao = *(const float4*)&ao[base];
  float4 ue, ua;
  ue.x = tm*vei.x + om*veo.x; ue.y = tm*vei.y + om*veo.y;
  ue.z = tm*vei.z + om*veo.z; ue.w = tm*vei.w + om*veo.w;
  ua.x = tm*vai.x + om*vao.x; ua.y = tm*vai.y + om*vao.y;
  ua.z = tm*vai.z + om*vao.z; ua.w = tm*vai.w + om*vao.w;
  *(float4*)&ws[OFF_UE + base] = ue;
  *(float4*)&ws[OFF_UA + base] = ua;
  float4 wqe = *(const float4*)&ws[WQE + (size_t)b*D + d0];
  float4 wqa = *(const float4*)&ws[WQA + (size_t)b*D + d0];
  float se = ue.x*wqe.x + ue.y*wqe.y + ue.z*wqe.z + ue.w*wqe.w;
  float sa = ua.x*wqa.x + ua.y*wqa.y + ua.z*wqa.z + ua.w*wqa.w;
  se = wave_sum(se); sa = wave_sum(sa);
  if ((threadIdx.x & 63) == 0) {
    size_t row = base >> 8;
    ws[OFF_LEU + row] = se;
    ws[OFF_LAU + row] = sa;
  }
}

// --- s1 = h.a1 ; s2 = h.a2 + (bef+aft).ca2 + c2 -------------------------------
__global__ __launch_bounds__(256) void k_s12(
    const float* __restrict__ bef, const float* __restrict__ aft,
    const float* __restrict__ a, float* __restrict__ ws)
{
  int wid  = (int)(((size_t)blockIdx.x*256 + threadIdx.x) >> 6);
  int lane = threadIdx.x & 63;
  int d0 = lane << 2;
  float4 a1 = *(const float4*)&a[d0];
  float4 a2 = *(const float4*)&a[D + d0];
  float4 cv = *(const float4*)&ws[CA2 + d0];
  float c2  = ws[C2c];
  for (int rr = 0; rr < 4; ++rr) {
    int row = wid*4 + rr;
    float4 h4 = *(const float4*)&ws[OFF_H + (size_t)row*D + d0];
    float4 b4 = *(const float4*)&bef[(size_t)row*D + d0];
    float4 f4 = *(const float4*)&aft[(size_t)row*D + d0];
    float s1 = h4.x*a1.x + h4.y*a1.y + h4.z*a1.z + h4.w*a1.w;
    float s2 = h4.x*a2.x + h4.y*a2.y + h4.z*a2.z + h4.w*a2.w
             + (b4.x+f4.x)*cv.x + (b4.y+f4.y)*cv.y
             + (b4.z+f4.z)*cv.z + (b4.w+f4.w)*cv.w;
    s1 = wave_sum(s1); s2 = wave_sum(s2);
    if (lane == 0) { ws[OFF_S1 + row] = s1; ws[OFF_S2 + row] = s2 + c2; }
  }
}

// --- R5: partial rank counts over 128-value k-chunks ---------------------------
__global__ __launch_bounds__(256) void k_cnt2(float* __restrict__ ws)
{
  int jb = blockIdx.x;          // 0..7
  int kb = blockIdx.y;          // 0..15
  int b  = blockIdx.z;
  int tid = threadIdx.x;
  __shared__ float ck[128];
  if (tid < 32)
    *(float4*)&ck[tid*4] = *(const float4*)&ws[OFF_S2 + (size_t)b*N + kb*128 + tid*4];
  __syncthreads();
  int j = jb*256 + tid;
  float v = ws[OFF_S2 + (size_t)b*N + j];
  int kg = kb*128;
  int cnt = 0;
#pragma unroll
  for (int k = 0; k < 128; k += 16) {
    float4 u0 = *(const float4*)&ck[k];
    float4 u1 = *(const float4*)&ck[k+4];
    float4 u2 = *(const float4*)&ck[k+8];
    float4 u3 = *(const float4*)&ck[k+12];
    cnt += (u0.x < v) || (u0.x == v && (kg+k+ 0) < j);
    cnt += (u0.y < v) || (u0.y == v && (kg+k+ 1) < j);
    cnt += (u0.z < v) || (u0.z == v && (kg+k+ 2) < j);
    cnt += (u0.w < v) || (u0.w == v && (kg+k+ 3) < j);
    cnt += (u1.x < v) || (u1.x == v && (kg+k+ 4) < j);
    cnt += (u1.y < v) || (u1.y == v && (kg+k+ 5) < j);
    cnt += (u1.z < v) || (u1.z == v && (kg+k+ 6) < j);
    cnt += (u1.w < v) || (u1.w == v && (kg+k+ 7) < j);
    cnt += (u2.x < v) || (u2.x == v && (kg+k+ 8) < j);
    cnt += (u2.y < v) || (u2.y == v && (kg+k+ 9) < j);
    cnt += (u2.z < v) || (u2.z == v && (kg+k+10) < j);
    cnt += (u2.w < v) || (u2.w == v && (kg+k+11) < j);
    cnt += (u3.x < v) || (u3.x == v && (kg+k+12) < j);
    cnt += (u3.y < v) || (u3.y == v && (kg+k+13) < j);
    cnt += (u3.z < v) || (u3.z == v && (kg+k+14) < j);
    cnt += (u3.w < v) || (u3.w == v && (kg+k+15) < j);
  }
  ((int*)ws)[OFF_PCNT + ((size_t)(b*16 + kb))*N + j] = cnt;
}

// --- R5: sum partial counts, scatter sorted SV/SIDX/WP/WN ----------------------
__global__ __launch_bounds__(256) void k_cntfin(float* __restrict__ ws)
{
  int b = blockIdx.y;
  int j = blockIdx.x*256 + threadIdx.x;
  int cnt = 0;
#pragma unroll
  for (int kb = 0; kb < 16; ++kb)
    cnt += ((const int*)ws)[OFF_PCNT + ((size_t)(b*16 + kb))*N + j];
  float v = ws[OFF_S2 + (size_t)b*N + j];
  size_t o = (size_t)b*N + cnt;
  ws[OFF_SV + o] = v;
  ((int*)ws)[OFF_SIDX + o] = j;
  ws[OFF_WP + o] = expf(v);
  ws[OFF_WN + o] = expf(ALPHA*v);
}

// --- R4: scalar prefix sums of sorted WP/WN -> ZP/ZN ---------------------------
__global__ __launch_bounds__(1024) void k_scan(float* __restrict__ ws)
{
  int b = blockIdx.x, m = blockIdx.y, t = threadIdx.x;
  const float* src = ws + (m ? OFF_WN : OFF_WP) + (size_t)b*N;
  float* dst = ws + (m ? OFF_ZN : OFF_ZP) + (size_t)b*(N+1);
  __shared__ float buf[N];
  buf[t] = src[t]; buf[t + 1024] = src[t + 1024];
  __syncthreads();
  for (int off = 1; off < N; off <<= 1) {
    float v0 = (t >= off)        ? buf[t - off]        : 0.f;
    float v1 = (t + 1024 >= off) ? buf[t + 1024 - off] : 0.f;
    __syncthreads();
    buf[t] += v0; buf[t + 1024] += v1;
    __syncthreads();
  }
  if (t == 0) dst[0] = 0.f;
  dst[t + 1]    = buf[t];
  dst[t + 1025] = buf[t + 1024];
}

// --- R1: per-row rank + folded softmax coefficients ----------------------------
__global__ __launch_bounds__(256) void k_rank(float* __restrict__ ws)
{
  int b = blockIdx.y;
  int i = blockIdx.x * 256 + threadIdx.x;
  __shared__ float sv[N];
  for (int r = threadIdx.x; r < N; r += 256) sv[r] = ws[OFF_SV + (size_t)b*N + r];
  __syncthreads();
  float s1i = ws[OFF_S1 + (size_t)b*N + i];
  float th = -s1i;
  int lo = 0, hi = N;
  while (lo < hi) { int mid = (lo + hi) >> 1; if (sv[mid] <= th) lo = mid + 1; else hi = mid; }
  int r = lo;
  float ep = expf(s1i), en = expf(ALPHA*s1i);
  float zp  = ws[OFF_ZP + (size_t)b*(N+1) + r];
  float zn  = ws[OFF_ZN + (size_t)b*(N+1) + r];
  float zpT = ws[OFF_ZP + (size_t)b*(N+1) + N];
  float den = ep*(zpT - zp) + en*zn;
  ((int*)ws)[OFF_RNK + (size_t)b*N + i] = r;
  ws[OFF_C0 + (size_t)b*N + i] = ep/den;
  ws[OFF_C1 + (size_t)b*N + i] = en/den;
}

// --- vector partials over sorted order ----------------------------------------
__global__ __launch_bounds__(256) void k_p1(float* __restrict__ ws)
{
  int c = blockIdx.x, b = blockIdx.y, d = threadIdx.x;
  const int*   sidx = (const int*)ws + OFF_SIDX + (size_t)b*N;
  const float* wp = ws + OFF_WP + (size_t)b*N;
  const float* wn = ws + OFF_WN + (size_t)b*N;
  const float* h  = ws + OFF_H + (size_t)b*N*D;
  float ap = 0.f, an = 0.f;
  for (int r = c*64; r < c*64 + 64; ++r) {
    float hv = h[(size_t)sidx[r]*D + d];
    ap += wp[r]*hv; an += wn[r]*hv;
  }
  ws[OFF_PARTP + ((size_t)b*32 + c)*D + d] = ap;
  ws[OFF_PARTN + ((size_t)b*32 + c)*D + d] = an;
}

// --- R4: p3 computes its own chunk offset --------------------------------------
__global__ __launch_bounds__(256) void k_p3(float* __restrict__ ws)
{
  int c = blockIdx.x, b = blockIdx.y, d = threadIdx.x;
  const int*   sidx = (const int*)ws + OFF_SIDX + (size_t)b*N;
  const float* wp = ws + OFF_WP + (size_t)b*N;
  const float* wn = ws + OFF_WN + (size_t)b*N;
  const float* h  = ws + OFF_H + (size_t)b*N*D;
  float ap = 0.f, an = 0.f;
  for (int c2 = 0; c2 < c; ++c2) {
    ap += ws[OFF_PARTP + ((size_t)b*32 + c2)*D + d];
    an += ws[OFF_PARTN + ((size_t)b*32 + c2)*D + d];
  }
  for (int r = c*64; r < c*64 + 64; ++r) {
    ws[OFF_PPOS + ((size_t)b*(N+1) + r)*D + d] = ap;
    ws[OFF_PNEG + ((size_t)b*(N+1) + r)*D + d] = an;
    float hv = h[(size_t)sidx[r]*D + d];
    ap += wp[r]*hv; an += wn[r]*hv;
  }
  if (c == 31) {
    ws[OFF_PPOS + ((size_t)b*(N+1) + N)*D + d] = ap;
    ws[OFF_PNEG + ((size_t)b*(N+1) + N)*D + d] = an;
  }
}

// --- R6: h_prime gather + hp-part of logits (u-part comes from LEU/LAU) -------
__global__ __launch_bounds__(256) void k_hprime2(float* __restrict__ ws)
{
  int b = blockIdx.y, d = threadIdx.x;
  int i0 = blockIdx.x * 8;
  float totp = ws[OFF_PPOS + ((size_t)b*(N+1) + N)*D + d];
  float kqe = ws[KQE + (size_t)b*D + d];
  float kqa = ws[KQA + (size_t)b*D + d];
  float se[8], sa[8];
#pragma unroll
  for (int ii = 0; ii < 8; ++ii) {
    int i = i0 + ii;
    int   r  = ((const int*)ws)[OFF_RNK + (size_t)b*N + i];
    float c0 = ws[OFF_C0 + (size_t)b*N + i];
    float c1 = ws[OFF_C1 + (size_t)b*N + i];
    float pp = ws[OFF_PPOS + ((size_t)b*(N+1) + r)*D + d];
    float pn = ws[OFF_PNEG + ((size_t)b*(N+1) + r)*D + d];
    float v = c0*(totp - pp) + c1*pn;
    ws[OFF_HP + ((size_t)b*N + i)*D + d] = v;
    se[ii] = v*kqe;
    sa[ii] = v*kqa;
  }
  __shared__ float lred[16][4];
  int w = d >> 6, lane = d & 63;
#pragma unroll
  for (int ii = 0; ii < 8; ++ii) {
    float s = wave_sum(se[ii]);
    if (lane == 0) lred[ii][w] = s;
    s = wave_sum(sa[ii]);
    if (lane == 0) lred[8 + ii][w] = s;
  }
  __syncthreads();
  if (d < 16) {
    float s = lred[d][0] + lred[d][1] + lred[d][2] + lred[d][3];
    size_t row = (size_t)b*N + i0 + (d & 7);
    if (d < 8) ws[OFF_LE + row] = (s + ws[OFF_LEU + row] + ws[CEc + b]) * INVS;
    else       ws[OFF_LA + row] = (s + ws[OFF_LAU + row] + ws[CAc + b]) * INVS;
  }
}

// --- R6: per-(b,measure) softmax max + inv-sum ---------------------------------
__global__ __launch_bounds__(256) void k_smred(float* __restrict__ ws)
{
  int b = blockIdx.x, m = blockIdx.y, t = threadIdx.x;
  const float* l = ws + (m ? OFF_LA : OFF_LE) + (size_t)b*N;
  __shared__ float red[256];
  float v[8];
  float mx = -1e30f;
#pragma unroll
  for (int k = 0; k < 8; ++k) { v[k] = l[t*8 + k]; mx = fmaxf(mx, v[k]); }
  red[t] = mx; __syncthreads();
  for (int s = 128; s > 0; s >>= 1) { if (t < s) red[t] = fmaxf(red[t], red[t+s]); __syncthreads(); }
  mx = red[0]; __syncthreads();
  float sum = 0.f;
#pragma unroll
  for (int k = 0; k < 8; ++k) sum += expf(v[k] - mx);
  red[t] = sum; __syncthreads();
  for (int s = 128; s > 0; s >>= 1) { if (t < s) red[t] += red[t+s]; __syncthreads(); }
  if (t == 0) {
    ws[(m ? SMXA : SMXE) + b] = mx;
    ws[(m ? SIVA : SIVE) + b] = 1.0f / red[0];
  }
}

// --- R6: fused tail: both measures' GEMMs + softmax-probs + final out ----------
// BM=32, BN=256 (full). 512 threads = 8 waves (2M x 4N); wave tile 16x64.
// k-loop stages hp/ue/ua tiles; acc{E,A}[j] += hp (x) vW + u (x) wW.
// Epilogue: out = relu(hp + inp + pe*(qce+Ve) + pa*(qca+Va)); probs written too.
__global__ __launch_bounds__(512) void k_mgemm2f(
    const float* __restrict__ inp, const ushort* __restrict__ bt,
    float* __restrict__ ws, float* __restrict__ out)
{
  __shared__ ushort Hs[32*40], Es[32*40], Zs[32*40];
  __shared__ float qec[256], qac[256];
  const int t = threadIdx.x;
  const int m0 = blockIdx.x * 32;
  const int b = m0 >> 11;
  const int lane = t & 63, w = t >> 6;
  const int wm = w >> 2, wn = w & 3;
  const int laneN = lane & 15, kg = lane >> 4;
  if (t < 256) qec[t] = ws[QCE + (size_t)b*D + t];
  else         qac[t - 256] = ws[QCA + (size_t)b*D + (t - 256)];
  const int srow = t >> 4, so = (t & 15) * 2;
  const float* hp = ws + OFF_HP;
  const float* ue = ws + OFF_UE;
  const float* ua = ws + OFF_UA;
  const ushort* Bve = bt + 1*65536;
  const ushort* Bwe = bt + 2*65536;
  const ushort* Bva = bt + 3*65536;
  const ushort* Bwa = bt + 4*65536;
  f32x4 accE[4] = {}, accA[4] = {};
  for (int k0 = 0; k0 < 256; k0 += 32) {
    __syncthreads();
    size_t abase = (size_t)(m0 + srow)*256 + k0 + so;
    float2 h2 = *(const float2*)&hp[abase];
    float2 e2 = *(const float2*)&ue[abase];
    float2 z2 = *(const float2*)&ua[abase];
    *(uint*)&Hs[srow*40 + so] = pk2bf(h2.x, h2.y);
    *(uint*)&Es[srow*40 + so] = pk2bf(e2.x, e2.y);
    *(uint*)&Zs[srow*40 + so] = pk2bf(z2.x, z2.y);
    __syncthreads();
    bf16x8 hf = *(const bf16x8*)&Hs[(wm*16 + laneN)*40 + kg*8];
    bf16x8 ef = *(const bf16x8*)&Es[(wm*16 + laneN)*40 + kg*8];
    bf16x8 zf = *(const bf16x8*)&Zs[(wm*16 + laneN)*40 + kg*8];
#pragma unroll
    for (int j = 0; j < 4; ++j) {
      size_t cb = (size_t)(wn*64 + j*16 + laneN)*256 + k0 + kg*8;
      bf16x8 bve = *(const bf16x8*)&Bve[cb];
      bf16x8 bwe = *(const bf16x8*)&Bwe[cb];
      bf16x8 bva = *(const bf16x8*)&Bva[cb];
      bf16x8 bwa = *(const bf16x8*)&Bwa[cb];
      accE[j] = __builtin_amdgcn_mfma_f32_16x16x32_bf16(hf, bve, accE[j], 0, 0, 0);
      accE[j] = __builtin_amdgcn_mfma_f32_16x16x32_bf16(ef, bwe, accE[j], 0, 0, 0);
      accA[j] = __builtin_amdgcn_mfma_f32_16x16x32_bf16(hf, bva, accA[j], 0, 0, 0);
      accA[j] = __builtin_amdgcn_mfma_f32_16x16x32_bf16(zf, bwa, accA[j], 0, 0, 0);
    }
  }
  float smxe = ws[SMXE + b], sive = ws[SIVE + b];
  float smxa = ws[SMXA + b], siva = ws[SIVA + b];
  if (t < 32) {
    size_t row = (size_t)m0 + t;
    int n = (int)(row & (N - 1));
    float pe = expf(ws[OFF_LE + row] - smxe) * sive;
    float pa = expf(ws[OFF_LA + row] - smxa) * siva;
    out[(size_t)B*N*D + (size_t)b*N + n] = pe;
    out[(size_t)B*N*D + (size_t)B*N + (size_t)b*N + n] = pa;
  }
#pragma unroll
  for (int r = 0; r < 4; ++r) {
    size_t row = (size_t)m0 + wm*16 + kg*4 + r;
    float pe = expf(ws[OFF_LE + row] - smxe) * sive;
    float pa = expf(ws[OFF_LA + row] - smxa) * siva;
#pragma unroll
    for (int j = 0; j < 4; ++j) {
      int col = wn*64 + j*16 + laneN;
      size_t idx = row*256 + col;
      float o = hp[idx] + inp[idx] + pe*(qec[col] + accE[j][r]) + pa*(qac[col] + accA[j][r]);
      out[idx] = fmaxf(o, 0.f);
    }
  }
}

extern "C" void kernel_launch(void* const* d_in, const int* in_sizes, int n_in,
                              void* d_out, int out_size, void* d_ws, size_t ws_size,
                              hipStream_t stream) {
  const float* inp  = (const float*)d_in[0];
  const float* emo  = (const float*)d_in[1];
  const float* bef  = (const float*)d_in[2];
  const float* aft  = (const float*)d_in[3];
  const float* ei   = (const float*)d_in[4];
  const float* eo   = (const float*)d_in[5];
  const float* ii   = (const float*)d_in[6];
  const float* io   = (const float*)d_in[7];
  const float* W    = (const float*)d_in[8];
  const float* a    = (const float*)d_in[9];
  const float* cskW = (const float*)d_in[10];
  const float* cskb = (const float*)d_in[11];
  const float* eW   = (const float*)d_in[12];
  const float* eb   = (const float*)d_in[13];
  const float* aW   = (const float*)d_in[14];
  const float* ab   = (const float*)d_in[15];
  const int*   cl   = (const int*)d_in[16];
  const int*   intra= (const int*)d_in[17];
  float* ws  = (float*)d_ws;
  float* out = (float*)d_out;
  ushort* bt = (ushort*)(ws + OFF_BT);

  k_btq<<<dim3(16, 7), 256, 0, stream>>>(W, eW, aW, inp, emo, cl, bt, ws);
  k_mgemmh<<<dim3(128, 2), 256, 0, stream>>>(inp, bt, ws + OFF_H);
  k_qfinish<<<dim3(B, 2), 256, 0, stream>>>(eb, ab, cskb, a, ws);
  k_rowdots<<<dim3(64, 17), 256, 0, stream>>>(eW, aW, cskW, a, ws);
  k_u<<<2048, 256, 0, stream>>>(ei, eo, ii, io, cl, intra, ws);
  k_s12<<<512, 256, 0, stream>>>(bef, aft, a, ws);
  k_cnt2<<<dim3(8, 16, B), 256, 0, stream>>>(ws);
  k_cntfin<<<dim3(8, B), 256, 0, stream>>>(ws);
  k_scan<<<dim3(B, 2), 1024, 0, stream>>>(ws);
  k_rank<<<dim3(8, B), 256, 0, stream>>>(ws);
  k_p1<<<dim3(32, B), 256, 0, stream>>>(ws);
  k_p3<<<dim3(32, B), 256, 0, stream>>>(ws);
  k_hprime2<<<dim3(256, B), 256, 0, stream>>>(ws);
  k_smred<<<dim3(B, 2), 256, 0, stream>>>(ws);
  k_mgemm2f<<<256, 512, 0, stream>>>(inp, bt, ws, out);
}

// Round 8
// 123.911 us; speedup vs baseline: 1.1479x; 1.1479x over previous
//
#include <hip/hip_runtime.h>
#include <math.h>

// ---------------------------------------------------------------------------
// Problem: B=4, N=2048, D=256.
// Key exact simplifications:
//  * intra+inter == 1  -> attention = softmax_j(leaky_relu(s1_i + s2_j)), no masks
//  * rank-1 + monotone -> h_prime via sorted-s2 prefix sums (O(N D), exact)
//  * evt / k_base / w_i / w_o folded into matvecs; only 3 big GEMMs remain
// R1: k_hprime -> k_rank + k_hprime2. R2: setup parallelized.
// R3: f32 VALU GEMMs -> bf16 MFMA. R4: logits fuse, p2 fold, GEMM merge.
// R5: rank-by-count (k_cnt2 + k_cntfin). R6: u.wq fold into k_u; tail fused
//     (probs+out in GEMM epilogue, VE/VA never materialized); btq merge.
//     R6 FAIL: k_mgemm2f 41us latency-bound (grid=256 -> 1 block/CU, 16
//     scattered L2 B-reads per thin barrier-bounded k-step).
// R7: retile tail + h-GEMM to BM=32/BN=128, grid (256,2)=512 blocks (2/CU),
//     4 waves x 32x32 tile, acc 32 VGPR. Same fused math, more TLP.
// ---------------------------------------------------------------------------

namespace {
constexpr int B = 4, N = 2048, D = 256;
constexpr float ALPHA = 0.2f;
constexpr float INVS  = 0.0625f;   // 1/sqrt(256)

// ws offsets (float elements)
constexpr size_t OFF_H     = 0;                       // (B,N,D)
constexpr size_t OFF_HP    = 2097152;                 // h_prime
constexpr size_t OFF_UE    = 4194304;                 // u_emo
constexpr size_t OFF_UA    = 6291456;                 // u_act
constexpr size_t OFF_PPOS  = 8388608;                 // (B,N+1,D) prefix
constexpr size_t OFF_PNEG  = 10486784;                // (B,N+1,D) prefix
constexpr size_t OFF_S1    = 12584960;                // (B,N)
constexpr size_t OFF_S2    = OFF_S1 + 8192;
constexpr size_t OFF_SV    = OFF_S2 + 8192;           // sorted s2
constexpr size_t OFF_SIDX  = OFF_SV + 8192;           // permutation (int)
constexpr size_t OFF_WP    = OFF_SIDX + 8192;         // e^{s2} sorted
constexpr size_t OFF_WN    = OFF_WP + 8192;           // e^{a s2} sorted
constexpr size_t OFF_ZP    = OFF_WN + 8192;           // (B,N+1) scalar prefix
constexpr size_t OFF_ZN    = OFF_ZP + 8196;
constexpr size_t OFF_PARTP = OFF_ZN + 8196;           // (B,32,D) chunk partials
constexpr size_t OFF_PARTN = OFF_PARTP + 32768;
constexpr size_t OFF_LE    = OFF_PARTN + 32768;       // emo logits
constexpr size_t OFF_LA    = OFF_LE + 8192;           // act logits
constexpr size_t OFF_SET   = OFF_LA + 8192;
constexpr size_t KQE = OFF_SET + 0;      // kW@q per batch (B,256)
constexpr size_t WQE = OFF_SET + 1024;
constexpr size_t KQA = OFF_SET + 2048;
constexpr size_t WQA = OFF_SET + 3072;
constexpr size_t QCE = OFF_SET + 4096;   // q + vb + wb
constexpr size_t QCA = OFF_SET + 5120;
constexpr size_t CA2 = OFF_SET + 6144;   // csk_W @ a2 (256)
constexpr size_t CEc = OFF_SET + 6400;   // q.(kb+wb) per batch
constexpr size_t CAc = OFF_SET + 6404;
constexpr size_t C2c = OFF_SET + 6408;   // 2*csk_b.a2
constexpr size_t OFF_RNK   = OFF_SET + 8192;          // (B,N) int
constexpr size_t OFF_C0    = OFF_RNK + 8192;          // ep/den
constexpr size_t OFF_C1    = OFF_C0 + 8192;           // en/den
constexpr size_t OFF_PARTQ = OFF_C1 + 8192;           // [m2][c16][b4][256]
constexpr size_t OFF_QE    = OFF_PARTQ + 32768;       // (B,256)
constexpr size_t OFF_QA    = OFF_QE + 1024;
constexpr size_t OFF_BT    = OFF_QA + 1024;           // 5 x 256x256 bf16 (ushort)
constexpr size_t OFF_PCNT  = OFF_BT + 163840;         // (B,16,N) int partials
constexpr size_t OFF_LEU   = OFF_PCNT + 131072;       // u.wq dots (B,N)
constexpr size_t OFF_LAU   = OFF_LEU + 8192;
constexpr size_t SMXE      = OFF_LAU + 8192;          // softmax max/inv (B each)
constexpr size_t SIVE      = SMXE + 4;
constexpr size_t SMXA      = SIVE + 4;
constexpr size_t SIVA      = SMXA + 4;
}

typedef __attribute__((ext_vector_type(8))) short bf16x8;
typedef __attribute__((ext_vector_type(4))) float f32x4;

__device__ inline float wave_sum(float v) {
#pragma unroll
  for (int off = 32; off > 0; off >>= 1) v += __shfl_xor(v, off, 64);
  return v;
}

__device__ inline ushort f2bf(float x) {
  union { float f; uint u; } v; v.f = x;
  return (ushort)((v.u + 0x7FFFu + ((v.u >> 16) & 1u)) >> 16);
}
__device__ inline uint pk2bf(float a, float b) {
  return (uint)f2bf(a) | ((uint)f2bf(b) << 16);
}

// --- R6: fused weight-transpose (y<5) + q split-k partials (y>=5) -------------
__global__ __launch_bounds__(256) void k_btq(
    const float* __restrict__ Wm, const float* __restrict__ eW,
    const float* __restrict__ aW, const float* __restrict__ inp,
    const float* __restrict__ emo, const int* __restrict__ cl,
    ushort* __restrict__ bt, float* __restrict__ ws)
{
  __shared__ float smem[64*65];
  if (blockIdx.y < 5) {
    int m = blockIdx.y;
    const float* src = (m == 0) ? Wm : (m == 1) ? eW + 3*65536 : (m == 2) ? eW
                     : (m == 3) ? aW + 3*65536 : aW;
    ushort* dst = bt + (size_t)m*65536;
    int k0 = (blockIdx.x >> 2)*64, n0 = (blockIdx.x & 3)*64;
    int r = threadIdx.x >> 2, c0 = (threadIdx.x & 3)*16;
#pragma unroll
    for (int cc = 0; cc < 16; cc += 4)
      *(float4*)&smem[r*65 + c0+cc] = *(const float4*)&src[(size_t)(k0+r)*256 + n0 + c0 + cc];
    __syncthreads();
    int n = threadIdx.x >> 2, kq = (threadIdx.x & 3)*16;
    uint4 o0, o1;
    o0.x = pk2bf(smem[(kq+ 0)*65+n], smem[(kq+ 1)*65+n]);
    o0.y = pk2bf(smem[(kq+ 2)*65+n], smem[(kq+ 3)*65+n]);
    o0.z = pk2bf(smem[(kq+ 4)*65+n], smem[(kq+ 5)*65+n]);
    o0.w = pk2bf(smem[(kq+ 6)*65+n], smem[(kq+ 7)*65+n]);
    o1.x = pk2bf(smem[(kq+ 8)*65+n], smem[(kq+ 9)*65+n]);
    o1.y = pk2bf(smem[(kq+10)*65+n], smem[(kq+11)*65+n]);
    o1.z = pk2bf(smem[(kq+12)*65+n], smem[(kq+13)*65+n]);
    o1.w = pk2bf(smem[(kq+14)*65+n], smem[(kq+15)*65+n]);
    *(uint4*)&dst[(size_t)(n0+n)*256 + k0 + kq]     = o0;
    *(uint4*)&dst[(size_t)(n0+n)*256 + k0 + kq + 8] = o1;
  } else {
    int c = blockIdx.x;          // k-chunk 0..15
    int m = blockIdx.y - 5;      // 0=emo, 1=act
    int d = threadIdx.x;
    if (d < 64) {
      int b = d >> 4, kk = d & 15;
      int t = cl[b] - 1;
      size_t idx = ((size_t)b*N + t)*D + c*16 + kk;
      float v = inp[idx];
      if (m == 0) v += emo[idx];
      smem[b*16 + kk] = v;
    }
    __syncthreads();
    const float* Wq = (m ? aW : eW) + (size_t)D*D;   // lin_W[1]
    float acc0 = 0.f, acc1 = 0.f, acc2 = 0.f, acc3 = 0.f;
#pragma unroll
    for (int kk = 0; kk < 16; ++kk) {
      int k = c*16 + kk;
      float w = Wq[(size_t)k*D + d];
      acc0 += smem[0*16+kk]*w; acc1 += smem[1*16+kk]*w;
      acc2 += smem[2*16+kk]*w; acc3 += smem[3*16+kk]*w;
    }
    size_t base = OFF_PARTQ + ((size_t)(m*16 + c)*4)*256 + d;
    ws[base + 0*256] = acc0; ws[base + 1*256] = acc1;
    ws[base + 2*256] = acc2; ws[base + 3*256] = acc3;
  }
}

// --- R7: h = inp @ W, BM=32/BN=128, grid (256,2) = 512 blocks -----------------
__global__ __launch_bounds__(256) void k_mgemmh(
    const float* __restrict__ A1, const ushort* __restrict__ bt,
    float* __restrict__ C)
{
  __shared__ ushort As[32*40];
  const int t = threadIdx.x;
  const int lane = t & 63, w = t >> 6;               // w = wave col-quarter
  const int laneN = lane & 15, kg = lane >> 4;
  const int m0 = blockIdx.x * 32, n0 = blockIdx.y * 128;
  const int srow = t >> 3, sc = (t & 7) * 4;
  f32x4 acc[2][2] = {};
  for (int k0 = 0; k0 < 256; k0 += 32) {
    __syncthreads();
    float4 f = *(const float4*)&A1[(size_t)(m0 + srow)*256 + k0 + sc];
    uint2 o; o.x = pk2bf(f.x, f.y); o.y = pk2bf(f.z, f.w);
    *(uint2*)&As[srow*40 + sc] = o;
    __syncthreads();
    bf16x8 af[2];
#pragma unroll
    for (int i = 0; i < 2; ++i)
      af[i] = *(const bf16x8*)&As[(i*16 + laneN)*40 + kg*8];
#pragma unroll
    for (int j = 0; j < 2; ++j) {
      bf16x8 bf = *(const bf16x8*)&bt[(size_t)(n0 + w*32 + j*16 + laneN)*256 + k0 + kg*8];
#pragma unroll
      for (int i = 0; i < 2; ++i)
        acc[i][j] = __builtin_amdgcn_mfma_f32_16x16x32_bf16(af[i], bf, acc[i][j], 0, 0, 0);
    }
  }
#pragma unroll
  for (int i = 0; i < 2; ++i)
#pragma unroll
    for (int j = 0; j < 2; ++j)
#pragma unroll
      for (int r = 0; r < 4; ++r)
        C[(size_t)(m0 + i*16 + kg*4 + r)*256 + n0 + w*32 + j*16 + laneN] = acc[i][j][r];
}

// --- R2: q = sum partials + qb; qc; scalar dots --------------------------------
__global__ __launch_bounds__(256) void k_qfinish(
    const float* __restrict__ eb, const float* __restrict__ ab,
    const float* __restrict__ cskb, const float* __restrict__ a,
    float* __restrict__ ws)
{
  int b = blockIdx.x, m = blockIdx.y, d = threadIdx.x;
  __shared__ float red[D];
  const float* bias = m ? ab : eb;
  float q = bias[D + d];
#pragma unroll
  for (int c = 0; c < 16; ++c)
    q += ws[OFF_PARTQ + ((size_t)(m*16 + c)*4 + b)*256 + d];
  ws[(m ? OFF_QA : OFF_QE) + (size_t)b*D + d] = q;
  ws[(m ? QCA : QCE) + (size_t)b*D + d] = q + bias[3*D + d] + bias[0*D + d];
  red[d] = q * (bias[2*D + d] + bias[0*D + d]);
  __syncthreads();
  for (int s = 128; s > 0; s >>= 1) { if (d < s) red[d] += red[d+s]; __syncthreads(); }
  if (d == 0) ws[(m ? CAc : CEc) + b] = red[0];
  if (m == 1 && b == 0) {
    __syncthreads();
    red[d] = cskb[d] * a[D + d];
    __syncthreads();
    for (int s = 128; s > 0; s >>= 1) { if (d < s) red[d] += red[d+s]; __syncthreads(); }
    if (d == 0) ws[C2c] = 2.0f * red[0];
  }
}

// --- R2: 17 row-major matvecs, wave-per-row, coalesced -------------------------
__global__ __launch_bounds__(256) void k_rowdots(
    const float* __restrict__ eW, const float* __restrict__ aW,
    const float* __restrict__ cskW, const float* __restrict__ a,
    float* __restrict__ ws)
{
  int job = blockIdx.y;
  int wid = threadIdx.x >> 6, lane = threadIdx.x & 63;
  int row = blockIdx.x*4 + wid;
  __shared__ float vec[D];
  const float* M; size_t outo;
  if (job < 16) {
    int b = job >> 2, m = (job >> 1) & 1, which = job & 1;
    const float* base = m ? aW : eW;
    M = base + (which ? 0 : (size_t)2*D*D);          // wW : kW
    if (threadIdx.x < D)
      vec[threadIdx.x] = ws[(m ? OFF_QA : OFF_QE) + (size_t)b*D + threadIdx.x];
    outo = (which ? (m ? WQA : WQE) : (m ? KQA : KQE)) + (size_t)b*D;
  } else {
    M = cskW;
    if (threadIdx.x < D) vec[threadIdx.x] = a[D + threadIdx.x];
    outo = CA2;
  }
  __syncthreads();
  float4 w = *reinterpret_cast<const float4*>(&M[(size_t)row*D + lane*4]);
  float s = w.x*vec[lane*4] + w.y*vec[lane*4+1] + w.z*vec[lane*4+2] + w.w*vec[lane*4+3];
  s = wave_sum(s);
  if (lane == 0) ws[outo + row] = s;
}

// --- R6: u = select + u.wq row dots (one wave == one row) ---------------------
__global__ __launch_bounds__(256) void k_u(
    const float* __restrict__ ei, const float* __restrict__ eo,
    const float* __restrict__ ai, const float* __restrict__ ao,
    const int* __restrict__ cl, const int* __restrict__ intra,
    float* __restrict__ ws)
{
  size_t g = (size_t)blockIdx.x*256 + threadIdx.x;
  size_t base = g << 2;
  int b = (int)(base >> 19);              // N*D = 2^19
  int n = (int)((base >> 8) & (N - 1));
  int d0 = (int)(base & (D - 1));
  int t = cl[b] - 1;
  float tm = (float)intra[(size_t)b*N*N + (size_t)t*N + n];
  float om = 1.0f - tm;
  float4 vei = *(const float4*)&ei[base];
  float4 veo = *(const float4*)&eo[base];
  float4 vai = *(const float4*)&ai[base];
  float4 vao = *(const float4*)&ao[base];
  float4 ue, ua;
  ue.x = tm*vei.x + om*veo.x; ue.y = tm*vei.y + om*veo.y;
  ue.z = tm*vei.z + om*veo.z; ue.w = tm*vei.w + om*veo.w;
  ua.x = tm*vai.x + om*vao.x; ua.y = tm*vai.y + om*vao.y;
  ua.z = tm*vai.z + om*vao.z; ua.w = tm*vai.w + om*vao.w;
  *(float4*)&ws[OFF_UE + base] = ue;
  *(float4*)&ws[OFF_UA + base] = ua;
  float4 wqe = *(const float4*)&ws[WQE + (size_t)b*D + d0];
  float4 wqa = *(const float4*)&ws[WQA + (size_t)b*D + d0];
  float se = ue.x*wqe.x + ue.y*wqe.y + ue.z*wqe.z + ue.w*wqe.w;
  float sa = ua.x*wqa.x + ua.y*wqa.y + ua.z*wqa.z + ua.w*wqa.w;
  se = wave_sum(se); sa = wave_sum(sa);
  if ((threadIdx.x & 63) == 0) {
    size_t row = base >> 8;
    ws[OFF_LEU + row] = se;
    ws[OFF_LAU + row] = sa;
  }
}

// --- s1 = h.a1 ; s2 = h.a2 + (bef+aft).ca2 + c2 -------------------------------
__global__ __launch_bounds__(256) void k_s12(
    const float* __restrict__ bef, const float* __restrict__ aft,
    const float* __restrict__ a, float* __restrict__ ws)
{
  int wid  = (int)(((size_t)blockIdx.x*256 + threadIdx.x) >> 6);
  int lane = threadIdx.x & 63;
  int d0 = lane << 2;
  float4 a1 = *(const float4*)&a[d0];
  float4 a2 = *(const float4*)&a[D + d0];
  float4 cv = *(const float4*)&ws[CA2 + d0];
  float c2  = ws[C2c];
  for (int rr = 0; rr < 4; ++rr) {
    int row = wid*4 + rr;
    float4 h4 = *(const float4*)&ws[OFF_H + (size_t)row*D + d0];
    float4 b4 = *(const float4*)&bef[(size_t)row*D + d0];
    float4 f4 = *(const float4*)&aft[(size_t)row*D + d0];
    float s1 = h4.x*a1.x + h4.y*a1.y + h4.z*a1.z + h4.w*a1.w;
    float s2 = h4.x*a2.x + h4.y*a2.y + h4.z*a2.z + h4.w*a2.w
             + (b4.x+f4.x)*cv.x + (b4.y+f4.y)*cv.y
             + (b4.z+f4.z)*cv.z + (b4.w+f4.w)*cv.w;
    s1 = wave_sum(s1); s2 = wave_sum(s2);
    if (lane == 0) { ws[OFF_S1 + row] = s1; ws[OFF_S2 + row] = s2 + c2; }
  }
}

// --- R5: partial rank counts over 128-value k-chunks ---------------------------
__global__ __launch_bounds__(256) void k_cnt2(float* __restrict__ ws)
{
  int jb = blockIdx.x;          // 0..7
  int kb = blockIdx.y;          // 0..15
  int b  = blockIdx.z;
  int tid = threadIdx.x;
  __shared__ float ck[128];
  if (tid < 32)
    *(float4*)&ck[tid*4] = *(const float4*)&ws[OFF_S2 + (size_t)b*N + kb*128 + tid*4];
  __syncthreads();
  int j = jb*256 + tid;
  float v = ws[OFF_S2 + (size_t)b*N + j];
  int kg = kb*128;
  int cnt = 0;
#pragma unroll
  for (int k = 0; k < 128; k += 16) {
    float4 u0 = *(const float4*)&ck[k];
    float4 u1 = *(const float4*)&ck[k+4];
    float4 u2 = *(const float4*)&ck[k+8];
    float4 u3 = *(const float4*)&ck[k+12];
    cnt += (u0.x < v) || (u0.x == v && (kg+k+ 0) < j);
    cnt += (u0.y < v) || (u0.y == v && (kg+k+ 1) < j);
    cnt += (u0.z < v) || (u0.z == v && (kg+k+ 2) < j);
    cnt += (u0.w < v) || (u0.w == v && (kg+k+ 3) < j);
    cnt += (u1.x < v) || (u1.x == v && (kg+k+ 4) < j);
    cnt += (u1.y < v) || (u1.y == v && (kg+k+ 5) < j);
    cnt += (u1.z < v) || (u1.z == v && (kg+k+ 6) < j);
    cnt += (u1.w < v) || (u1.w == v && (kg+k+ 7) < j);
    cnt += (u2.x < v) || (u2.x == v && (kg+k+ 8) < j);
    cnt += (u2.y < v) || (u2.y == v && (kg+k+ 9) < j);
    cnt += (u2.z < v) || (u2.z == v && (kg+k+10) < j);
    cnt += (u2.w < v) || (u2.w == v && (kg+k+11) < j);
    cnt += (u3.x < v) || (u3.x == v && (kg+k+12) < j);
    cnt += (u3.y < v) || (u3.y == v && (kg+k+13) < j);
    cnt += (u3.z < v) || (u3.z == v && (kg+k+14) < j);
    cnt += (u3.w < v) || (u3.w == v && (kg+k+15) < j);
  }
  ((int*)ws)[OFF_PCNT + ((size_t)(b*16 + kb))*N + j] = cnt;
}

// --- R5: sum partial counts, scatter sorted SV/SIDX/WP/WN ----------------------
__global__ __launch_bounds__(256) void k_cntfin(float* __restrict__ ws)
{
  int b = blockIdx.y;
  int j = blockIdx.x*256 + threadIdx.x;
  int cnt = 0;
#pragma unroll
  for (int kb = 0; kb < 16; ++kb)
    cnt += ((const int*)ws)[OFF_PCNT + ((size_t)(b*16 + kb))*N + j];
  float v = ws[OFF_S2 + (size_t)b*N + j];
  size_t o = (size_t)b*N + cnt;
  ws[OFF_SV + o] = v;
  ((int*)ws)[OFF_SIDX + o] = j;
  ws[OFF_WP + o] = expf(v);
  ws[OFF_WN + o] = expf(ALPHA*v);
}

// --- R4: scalar prefix sums of sorted WP/WN -> ZP/ZN ---------------------------
__global__ __launch_bounds__(1024) void k_scan(float* __restrict__ ws)
{
  int b = blockIdx.x, m = blockIdx.y, t = threadIdx.x;
  const float* src = ws + (m ? OFF_WN : OFF_WP) + (size_t)b*N;
  float* dst = ws + (m ? OFF_ZN : OFF_ZP) + (size_t)b*(N+1);
  __shared__ float buf[N];
  buf[t] = src[t]; buf[t + 1024] = src[t + 1024];
  __syncthreads();
  for (int off = 1; off < N; off <<= 1) {
    float v0 = (t >= off)        ? buf[t - off]        : 0.f;
    float v1 = (t + 1024 >= off) ? buf[t + 1024 - off] : 0.f;
    __syncthreads();
    buf[t] += v0; buf[t + 1024] += v1;
    __syncthreads();
  }
  if (t == 0) dst[0] = 0.f;
  dst[t + 1]    = buf[t];
  dst[t + 1025] = buf[t + 1024];
}

// --- R1: per-row rank + folded softmax coefficients ----------------------------
__global__ __launch_bounds__(256) void k_rank(float* __restrict__ ws)
{
  int b = blockIdx.y;
  int i = blockIdx.x * 256 + threadIdx.x;
  __shared__ float sv[N];
  for (int r = threadIdx.x; r < N; r += 256) sv[r] = ws[OFF_SV + (size_t)b*N + r];
  __syncthreads();
  float s1i = ws[OFF_S1 + (size_t)b*N + i];
  float th = -s1i;
  int lo = 0, hi = N;
  while (lo < hi) { int mid = (lo + hi) >> 1; if (sv[mid] <= th) lo = mid + 1; else hi = mid; }
  int r = lo;
  float ep = expf(s1i), en = expf(ALPHA*s1i);
  float zp  = ws[OFF_ZP + (size_t)b*(N+1) + r];
  float zn  = ws[OFF_ZN + (size_t)b*(N+1) + r];
  float zpT = ws[OFF_ZP + (size_t)b*(N+1) + N];
  float den = ep*(zpT - zp) + en*zn;
  ((int*)ws)[OFF_RNK + (size_t)b*N + i] = r;
  ws[OFF_C0 + (size_t)b*N + i] = ep/den;
  ws[OFF_C1 + (size_t)b*N + i] = en/den;
}

// --- vector partials over sorted order ----------------------------------------
__global__ __launch_bounds__(256) void k_p1(float* __restrict__ ws)
{
  int c = blockIdx.x, b = blockIdx.y, d = threadIdx.x;
  const int*   sidx = (const int*)ws + OFF_SIDX + (size_t)b*N;
  const float* wp = ws + OFF_WP + (size_t)b*N;
  const float* wn = ws + OFF_WN + (size_t)b*N;
  const float* h  = ws + OFF_H + (size_t)b*N*D;
  float ap = 0.f, an = 0.f;
  for (int r = c*64; r < c*64 + 64; ++r) {
    float hv = h[(size_t)sidx[r]*D + d];
    ap += wp[r]*hv; an += wn[r]*hv;
  }
  ws[OFF_PARTP + ((size_t)b*32 + c)*D + d] = ap;
  ws[OFF_PARTN + ((size_t)b*32 + c)*D + d] = an;
}

// --- R4: p3 computes its own chunk offset --------------------------------------
__global__ __launch_bounds__(256) void k_p3(float* __restrict__ ws)
{
  int c = blockIdx.x, b = blockIdx.y, d = threadIdx.x;
  const int*   sidx = (const int*)ws + OFF_SIDX + (size_t)b*N;
  const float* wp = ws + OFF_WP + (size_t)b*N;
  const float* wn = ws + OFF_WN + (size_t)b*N;
  const float* h  = ws + OFF_H + (size_t)b*N*D;
  float ap = 0.f, an = 0.f;
  for (int c2 = 0; c2 < c; ++c2) {
    ap += ws[OFF_PARTP + ((size_t)b*32 + c2)*D + d];
    an += ws[OFF_PARTN + ((size_t)b*32 + c2)*D + d];
  }
  for (int r = c*64; r < c*64 + 64; ++r) {
    ws[OFF_PPOS + ((size_t)b*(N+1) + r)*D + d] = ap;
    ws[OFF_PNEG + ((size_t)b*(N+1) + r)*D + d] = an;
    float hv = h[(size_t)sidx[r]*D + d];
    ap += wp[r]*hv; an += wn[r]*hv;
  }
  if (c == 31) {
    ws[OFF_PPOS + ((size_t)b*(N+1) + N)*D + d] = ap;
    ws[OFF_PNEG + ((size_t)b*(N+1) + N)*D + d] = an;
  }
}

// --- R6: h_prime gather + hp-part of logits (u-part comes from LEU/LAU) -------
__global__ __launch_bounds__(256) void k_hprime2(float* __restrict__ ws)
{
  int b = blockIdx.y, d = threadIdx.x;
  int i0 = blockIdx.x * 8;
  float totp = ws[OFF_PPOS + ((size_t)b*(N+1) + N)*D + d];
  float kqe = ws[KQE + (size_t)b*D + d];
  float kqa = ws[KQA + (size_t)b*D + d];
  float se[8], sa[8];
#pragma unroll
  for (int ii = 0; ii < 8; ++ii) {
    int i = i0 + ii;
    int   r  = ((const int*)ws)[OFF_RNK + (size_t)b*N + i];
    float c0 = ws[OFF_C0 + (size_t)b*N + i];
    float c1 = ws[OFF_C1 + (size_t)b*N + i];
    float pp = ws[OFF_PPOS + ((size_t)b*(N+1) + r)*D + d];
    float pn = ws[OFF_PNEG + ((size_t)b*(N+1) + r)*D + d];
    float v = c0*(totp - pp) + c1*pn;
    ws[OFF_HP + ((size_t)b*N + i)*D + d] = v;
    se[ii] = v*kqe;
    sa[ii] = v*kqa;
  }
  __shared__ float lred[16][4];
  int w = d >> 6, lane = d & 63;
#pragma unroll
  for (int ii = 0; ii < 8; ++ii) {
    float s = wave_sum(se[ii]);
    if (lane == 0) lred[ii][w] = s;
    s = wave_sum(sa[ii]);
    if (lane == 0) lred[8 + ii][w] = s;
  }
  __syncthreads();
  if (d < 16) {
    float s = lred[d][0] + lred[d][1] + lred[d][2] + lred[d][3];
    size_t row = (size_t)b*N + i0 + (d & 7);
    if (d < 8) ws[OFF_LE + row] = (s + ws[OFF_LEU + row] + ws[CEc + b]) * INVS;
    else       ws[OFF_LA + row] = (s + ws[OFF_LAU + row] + ws[CAc + b]) * INVS;
  }
}

// --- R6: per-(b,measure) softmax max + inv-sum ---------------------------------
__global__ __launch_bounds__(256) void k_smred(float* __restrict__ ws)
{
  int b = blockIdx.x, m = blockIdx.y, t = threadIdx.x;
  const float* l = ws + (m ? OFF_LA : OFF_LE) + (size_t)b*N;
  __shared__ float red[256];
  float v[8];
  float mx = -1e30f;
#pragma unroll
  for (int k = 0; k < 8; ++k) { v[k] = l[t*8 + k]; mx = fmaxf(mx, v[k]); }
  red[t] = mx; __syncthreads();
  for (int s = 128; s > 0; s >>= 1) { if (t < s) red[t] = fmaxf(red[t], red[t+s]); __syncthreads(); }
  mx = red[0]; __syncthreads();
  float sum = 0.f;
#pragma unroll
  for (int k = 0; k < 8; ++k) sum += expf(v[k] - mx);
  red[t] = sum; __syncthreads();
  for (int s = 128; s > 0; s >>= 1) { if (t < s) red[t] += red[t+s]; __syncthreads(); }
  if (t == 0) {
    ws[(m ? SMXA : SMXE) + b] = mx;
    ws[(m ? SIVA : SIVE) + b] = 1.0f / red[0];
  }
}

// --- R7: fused tail, BM=32/BN=128, grid (256,2) = 512 blocks, 4 waves ---------
// Wave tile 32x32: acc[meas][i][j] (8 f32x4 = 32 VGPR). Both measures per block.
// Epilogue: probs (y==0 blocks) + out = relu(hp+inp+pe*(qce+Ve)+pa*(qca+Va)).
__global__ __launch_bounds__(256) void k_tail(
    const float* __restrict__ inp, const ushort* __restrict__ bt,
    float* __restrict__ ws, float* __restrict__ out)
{
  __shared__ ushort Hs[32*40], Es[32*40], Zs[32*40];
  __shared__ float qec[256], qac[256];
  const int t = threadIdx.x;
  const int m0 = blockIdx.x * 32, n0 = blockIdx.y * 128;
  const int b = m0 >> 11;
  const int lane = t & 63, w = t >> 6;               // w = wave col-quarter
  const int laneN = lane & 15, kg = lane >> 4;
  qec[t] = ws[QCE + (size_t)b*D + t];
  qac[t] = ws[QCA + (size_t)b*D + t];
  const int srow = t >> 3, sc = (t & 7) * 4;
  const float* hp = ws + OFF_HP;
  const float* ue = ws + OFF_UE;
  const float* ua = ws + OFF_UA;
  const ushort* Bve = bt + 1*65536;
  const ushort* Bwe = bt + 2*65536;
  const ushort* Bva = bt + 3*65536;
  const ushort* Bwa = bt + 4*65536;
  f32x4 accE[2][2] = {}, accA[2][2] = {};
  for (int k0 = 0; k0 < 256; k0 += 32) {
    __syncthreads();
    size_t abase = (size_t)(m0 + srow)*256 + k0 + sc;
    float4 h4 = *(const float4*)&hp[abase];
    float4 e4 = *(const float4*)&ue[abase];
    float4 z4 = *(const float4*)&ua[abase];
    uint2 oh; oh.x = pk2bf(h4.x, h4.y); oh.y = pk2bf(h4.z, h4.w);
    uint2 oe; oe.x = pk2bf(e4.x, e4.y); oe.y = pk2bf(e4.z, e4.w);
    uint2 oz; oz.x = pk2bf(z4.x, z4.y); oz.y = pk2bf(z4.z, z4.w);
    *(uint2*)&Hs[srow*40 + sc] = oh;
    *(uint2*)&Es[srow*40 + sc] = oe;
    *(uint2*)&Zs[srow*40 + sc] = oz;
    __syncthreads();
    bf16x8 hf[2], ef[2], zf[2];
#pragma unroll
    for (int i = 0; i < 2; ++i) {
      hf[i] = *(const bf16x8*)&Hs[(i*16 + laneN)*40 + kg*8];
      ef[i] = *(const bf16x8*)&Es[(i*16 + laneN)*40 + kg*8];
      zf[i] = *(const bf16x8*)&Zs[(i*16 + laneN)*40 + kg*8];
    }
#pragma unroll
    for (int j = 0; j < 2; ++j) {
      size_t cb = (size_t)(n0 + w*32 + j*16 + laneN)*256 + k0 + kg*8;
      bf16x8 bve = *(const bf16x8*)&Bve[cb];
      bf16x8 bwe = *(const bf16x8*)&Bwe[cb];
      bf16x8 bva = *(const bf16x8*)&Bva[cb];
      bf16x8 bwa = *(const bf16x8*)&Bwa[cb];
#pragma unroll
      for (int i = 0; i < 2; ++i) {
        accE[i][j] = __builtin_amdgcn_mfma_f32_16x16x32_bf16(hf[i], bve, accE[i][j], 0, 0, 0);
        accE[i][j] = __builtin_amdgcn_mfma_f32_16x16x32_bf16(ef[i], bwe, accE[i][j], 0, 0, 0);
        accA[i][j] = __builtin_amdgcn_mfma_f32_16x16x32_bf16(hf[i], bva, accA[i][j], 0, 0, 0);
        accA[i][j] = __builtin_amdgcn_mfma_f32_16x16x32_bf16(zf[i], bwa, accA[i][j], 0, 0, 0);
      }
    }
  }
  float smxe = ws[SMXE + b], sive = ws[SIVE + b];
  float smxa = ws[SMXA + b], siva = ws[SIVA + b];
  if (blockIdx.y == 0 && t < 32) {
    size_t row = (size_t)m0 + t;
    int n = (int)(row & (N - 1));
    float pe = expf(ws[OFF_LE + row] - smxe) * sive;
    float pa = expf(ws[OFF_LA + row] - smxa) * siva;
    out[(size_t)B*N*D + (size_t)b*N + n] = pe;
    out[(size_t)B*N*D + (size_t)B*N + (size_t)b*N + n] = pa;
  }
#pragma unroll
  for (int i = 0; i < 2; ++i) {
#pragma unroll
    for (int r = 0; r < 4; ++r) {
      size_t row = (size_t)m0 + i*16 + kg*4 + r;
      float pe = expf(ws[OFF_LE + row] - smxe) * sive;
      float pa = expf(ws[OFF_LA + row] - smxa) * siva;
#pragma unroll
      for (int j = 0; j < 2; ++j) {
        int col = n0 + w*32 + j*16 + laneN;
        size_t idx = row*256 + col;
        float o = hp[idx] + inp[idx] + pe*(qec[col] + accE[i][j][r]) + pa*(qac[col] + accA[i][j][r]);
        out[idx] = fmaxf(o, 0.f);
      }
    }
  }
}

extern "C" void kernel_launch(void* const* d_in, const int* in_sizes, int n_in,
                              void* d_out, int out_size, void* d_ws, size_t ws_size,
                              hipStream_t stream) {
  const float* inp  = (const float*)d_in[0];
  const float* emo  = (const float*)d_in[1];
  const float* bef  = (const float*)d_in[2];
  const float* aft  = (const float*)d_in[3];
  const float* ei   = (const float*)d_in[4];
  const float* eo   = (const float*)d_in[5];
  const float* ii   = (const float*)d_in[6];
  const float* io   = (const float*)d_in[7];
  const float* W    = (const float*)d_in[8];
  const float* a    = (const float*)d_in[9];
  const float* cskW = (const float*)d_in[10];
  const float* cskb = (const float*)d_in[11];
  const float* eW   = (const float*)d_in[12];
  const float* eb   = (const float*)d_in[13];
  const float* aW   = (const float*)d_in[14];
  const float* ab   = (const float*)d_in[15];
  const int*   cl   = (const int*)d_in[16];
  const int*   intra= (const int*)d_in[17];
  float* ws  = (float*)d_ws;
  float* out = (float*)d_out;
  ushort* bt = (ushort*)(ws + OFF_BT);

  k_btq<<<dim3(16, 7), 256, 0, stream>>>(W, eW, aW, inp, emo, cl, bt, ws);
  k_mgemmh<<<dim3(256, 2), 256, 0, stream>>>(inp, bt, ws + OFF_H);
  k_qfinish<<<dim3(B, 2), 256, 0, stream>>>(eb, ab, cskb, a, ws);
  k_rowdots<<<dim3(64, 17), 256, 0, stream>>>(eW, aW, cskW, a, ws);
  k_u<<<2048, 256, 0, stream>>>(ei, eo, ii, io, cl, intra, ws);
  k_s12<<<512, 256, 0, stream>>>(bef, aft, a, ws);
  k_cnt2<<<dim3(8, 16, B), 256, 0, stream>>>(ws);
  k_cntfin<<<dim3(8, B), 256, 0, stream>>>(ws);
  k_scan<<<dim3(B, 2), 1024, 0, stream>>>(ws);
  k_rank<<<dim3(8, B), 256, 0, stream>>>(ws);
  k_p1<<<dim3(32, B), 256, 0, stream>>>(ws);
  k_p3<<<dim3(32, B), 256, 0, stream>>>(ws);
  k_hprime2<<<dim3(256, B), 256, 0, stream>>>(ws);
  k_smred<<<dim3(B, 2), 256, 0, stream>>>(ws);
  k_tail<<<dim3(256, 2), 256, 0, stream>>>(inp, bt, ws, out);
}

// Round 9
// 122.408 us; speedup vs baseline: 1.1620x; 1.0123x over previous
//
#include <hip/hip_runtime.h>
#include <math.h>

// ---------------------------------------------------------------------------
// Problem: B=4, N=2048, D=256.
// Key exact simplifications:
//  * intra+inter == 1  -> attention = softmax_j(leaky_relu(s1_i + s2_j)), no masks
//  * rank-1 + monotone -> h_prime via sorted-s2 prefix sums (O(N D), exact)
//  * evt / k_base / w_i / w_o folded into matvecs; only 3 big GEMMs remain
// R1: k_hprime -> k_rank + k_hprime2. R2: setup parallelized.
// R3: f32 VALU GEMMs -> bf16 MFMA. R4: logits fuse, p2 fold, GEMM merge.
// R5: rank-by-count (k_cnt2 + k_cntfin). R6: u.wq fold into k_u; tail fused
//     (probs+out in GEMM epilogue, VE/VA never materialized); btq merge.
//     R6 FAIL: k_mgemm2f 41us latency-bound (grid=256 -> 1 block/CU, 16
//     scattered L2 B-reads per thin barrier-bounded k-step).
// R7: retile tail + h-GEMM to BM=32/BN=128, grid (256,2)=512 blocks (2/CU),
//     4 waves x 32x32 tile, acc 32 VGPR. Same fused math, more TLP.
// ---------------------------------------------------------------------------

namespace {
constexpr int B = 4, N = 2048, D = 256;
constexpr float ALPHA = 0.2f;
constexpr float INVS  = 0.0625f;   // 1/sqrt(256)

// ws offsets (float elements)
constexpr size_t OFF_H     = 0;                       // (B,N,D)
constexpr size_t OFF_HP    = 2097152;                 // h_prime
constexpr size_t OFF_UE    = 4194304;                 // u_emo
constexpr size_t OFF_UA    = 6291456;                 // u_act
constexpr size_t OFF_PPOS  = 8388608;                 // (B,N+1,D) prefix
constexpr size_t OFF_PNEG  = 10486784;                // (B,N+1,D) prefix
constexpr size_t OFF_S1    = 12584960;                // (B,N)
constexpr size_t OFF_S2    = OFF_S1 + 8192;
constexpr size_t OFF_SV    = OFF_S2 + 8192;           // sorted s2
constexpr size_t OFF_SIDX  = OFF_SV + 8192;           // permutation (int)
constexpr size_t OFF_WP    = OFF_SIDX + 8192;         // e^{s2} sorted
constexpr size_t OFF_WN    = OFF_WP + 8192;           // e^{a s2} sorted
constexpr size_t OFF_ZP    = OFF_WN + 8192;           // (B,N+1) scalar prefix
constexpr size_t OFF_ZN    = OFF_ZP + 8196;
constexpr size_t OFF_PARTP = OFF_ZN + 8196;           // (B,32,D) chunk partials
constexpr size_t OFF_PARTN = OFF_PARTP + 32768;
constexpr size_t OFF_LE    = OFF_PARTN + 32768;       // emo logits
constexpr size_t OFF_LA    = OFF_LE + 8192;           // act logits
constexpr size_t OFF_SET   = OFF_LA + 8192;
constexpr size_t KQE = OFF_SET + 0;      // kW@q per batch (B,256)
constexpr size_t WQE = OFF_SET + 1024;
constexpr size_t KQA = OFF_SET + 2048;
constexpr size_t WQA = OFF_SET + 3072;
constexpr size_t QCE = OFF_SET + 4096;   // q + vb + wb
constexpr size_t QCA = OFF_SET + 5120;
constexpr size_t CA2 = OFF_SET + 6144;   // csk_W @ a2 (256)
constexpr size_t CEc = OFF_SET + 6400;   // q.(kb+wb) per batch
constexpr size_t CAc = OFF_SET + 6404;
constexpr size_t C2c = OFF_SET + 6408;   // 2*csk_b.a2
constexpr size_t OFF_RNK   = OFF_SET + 8192;          // (B,N) int
constexpr size_t OFF_C0    = OFF_RNK + 8192;          // ep/den
constexpr size_t OFF_C1    = OFF_C0 + 8192;           // en/den
constexpr size_t OFF_PARTQ = OFF_C1 + 8192;           // [m2][c16][b4][256]
constexpr size_t OFF_QE    = OFF_PARTQ + 32768;       // (B,256)
constexpr size_t OFF_QA    = OFF_QE + 1024;
constexpr size_t OFF_BT    = OFF_QA + 1024;           // 5 x 256x256 bf16 (ushort)
constexpr size_t OFF_PCNT  = OFF_BT + 163840;         // (B,16,N) int partials
constexpr size_t OFF_LEU   = OFF_PCNT + 131072;       // u.wq dots (B,N)
constexpr size_t OFF_LAU   = OFF_LEU + 8192;
constexpr size_t SMXE      = OFF_LAU + 8192;          // softmax max/inv (B each)
constexpr size_t SIVE      = SMXE + 4;
constexpr size_t SMXA      = SIVE + 4;
constexpr size_t SIVA      = SMXA + 4;
}

typedef __attribute__((ext_vector_type(8))) short bf16x8;
typedef __attribute__((ext_vector_type(4))) float f32x4;

__device__ inline float wave_sum(float v) {
#pragma unroll
  for (int off = 32; off > 0; off >>= 1) v += __shfl_xor(v, off, 64);
  return v;
}

__device__ inline ushort f2bf(float x) {
  union { float f; uint u; } v; v.f = x;
  return (ushort)((v.u + 0x7FFFu + ((v.u >> 16) & 1u)) >> 16);
}
__device__ inline uint pk2bf(float a, float b) {
  return (uint)f2bf(a) | ((uint)f2bf(b) << 16);
}

// --- R6: fused weight-transpose (y<5) + q split-k partials (y>=5) -------------
__global__ __launch_bounds__(256) void k_btq(
    const float* __restrict__ Wm, const float* __restrict__ eW,
    const float* __restrict__ aW, const float* __restrict__ inp,
    const float* __restrict__ emo, const int* __restrict__ cl,
    ushort* __restrict__ bt, float* __restrict__ ws)
{
  __shared__ float smem[64*65];
  if (blockIdx.y < 5) {
    int m = blockIdx.y;
    const float* src = (m == 0) ? Wm : (m == 1) ? eW + 3*65536 : (m == 2) ? eW
                     : (m == 3) ? aW + 3*65536 : aW;
    ushort* dst = bt + (size_t)m*65536;
    int k0 = (blockIdx.x >> 2)*64, n0 = (blockIdx.x & 3)*64;
    int r = threadIdx.x >> 2, c0 = (threadIdx.x & 3)*16;
#pragma unroll
    for (int cc = 0; cc < 16; cc += 4)
      *(float4*)&smem[r*65 + c0+cc] = *(const float4*)&src[(size_t)(k0+r)*256 + n0 + c0 + cc];
    __syncthreads();
    int n = threadIdx.x >> 2, kq = (threadIdx.x & 3)*16;
    uint4 o0, o1;
    o0.x = pk2bf(smem[(kq+ 0)*65+n], smem[(kq+ 1)*65+n]);
    o0.y = pk2bf(smem[(kq+ 2)*65+n], smem[(kq+ 3)*65+n]);
    o0.z = pk2bf(smem[(kq+ 4)*65+n], smem[(kq+ 5)*65+n]);
    o0.w = pk2bf(smem[(kq+ 6)*65+n], smem[(kq+ 7)*65+n]);
    o1.x = pk2bf(smem[(kq+ 8)*65+n], smem[(kq+ 9)*65+n]);
    o1.y = pk2bf(smem[(kq+10)*65+n], smem[(kq+11)*65+n]);
    o1.z = pk2bf(smem[(kq+12)*65+n], smem[(kq+13)*65+n]);
    o1.w = pk2bf(smem[(kq+14)*65+n], smem[(kq+15)*65+n]);
    *(uint4*)&dst[(size_t)(n0+n)*256 + k0 + kq]     = o0;
    *(uint4*)&dst[(size_t)(n0+n)*256 + k0 + kq + 8] = o1;
  } else {
    int c = blockIdx.x;          // k-chunk 0..15
    int m = blockIdx.y - 5;      // 0=emo, 1=act
    int d = threadIdx.x;
    if (d < 64) {
      int b = d >> 4, kk = d & 15;
      int t = cl[b] - 1;
      size_t idx = ((size_t)b*N + t)*D + c*16 + kk;
      float v = inp[idx];
      if (m == 0) v += emo[idx];
      smem[b*16 + kk] = v;
    }
    __syncthreads();
    const float* Wq = (m ? aW : eW) + (size_t)D*D;   // lin_W[1]
    float acc0 = 0.f, acc1 = 0.f, acc2 = 0.f, acc3 = 0.f;
#pragma unroll
    for (int kk = 0; kk < 16; ++kk) {
      int k = c*16 + kk;
      float w = Wq[(size_t)k*D + d];
      acc0 += smem[0*16+kk]*w; acc1 += smem[1*16+kk]*w;
      acc2 += smem[2*16+kk]*w; acc3 += smem[3*16+kk]*w;
    }
    size_t base = OFF_PARTQ + ((size_t)(m*16 + c)*4)*256 + d;
    ws[base + 0*256] = acc0; ws[base + 1*256] = acc1;
    ws[base + 2*256] = acc2; ws[base + 3*256] = acc3;
  }
}

// --- R7: h = inp @ W, BM=32/BN=128, grid (256,2) = 512 blocks -----------------
__global__ __launch_bounds__(256) void k_mgemmh(
    const float* __restrict__ A1, const ushort* __restrict__ bt,
    float* __restrict__ C)
{
  __shared__ ushort As[32*40];
  const int t = threadIdx.x;
  const int lane = t & 63, w = t >> 6;               // w = wave col-quarter
  const int laneN = lane & 15, kg = lane >> 4;
  const int m0 = blockIdx.x * 32, n0 = blockIdx.y * 128;
  const int srow = t >> 3, sc = (t & 7) * 4;
  f32x4 acc[2][2] = {};
  for (int k0 = 0; k0 < 256; k0 += 32) {
    __syncthreads();
    float4 f = *(const float4*)&A1[(size_t)(m0 + srow)*256 + k0 + sc];
    uint2 o; o.x = pk2bf(f.x, f.y); o.y = pk2bf(f.z, f.w);
    *(uint2*)&As[srow*40 + sc] = o;
    __syncthreads();
    bf16x8 af[2];
#pragma unroll
    for (int i = 0; i < 2; ++i)
      af[i] = *(const bf16x8*)&As[(i*16 + laneN)*40 + kg*8];
#pragma unroll
    for (int j = 0; j < 2; ++j) {
      bf16x8 bf = *(const bf16x8*)&bt[(size_t)(n0 + w*32 + j*16 + laneN)*256 + k0 + kg*8];
#pragma unroll
      for (int i = 0; i < 2; ++i)
        acc[i][j] = __builtin_amdgcn_mfma_f32_16x16x32_bf16(af[i], bf, acc[i][j], 0, 0, 0);
    }
  }
#pragma unroll
  for (int i = 0; i < 2; ++i)
#pragma unroll
    for (int j = 0; j < 2; ++j)
#pragma unroll
      for (int r = 0; r < 4; ++r)
        C[(size_t)(m0 + i*16 + kg*4 + r)*256 + n0 + w*32 + j*16 + laneN] = acc[i][j][r];
}

// --- R2: q = sum partials + qb; qc; scalar dots --------------------------------
__global__ __launch_bounds__(256) void k_qfinish(
    const float* __restrict__ eb, const float* __restrict__ ab,
    const float* __restrict__ cskb, const float* __restrict__ a,
    float* __restrict__ ws)
{
  int b = blockIdx.x, m = blockIdx.y, d = threadIdx.x;
  __shared__ float red[D];
  const float* bias = m ? ab : eb;
  float q = bias[D + d];
#pragma unroll
  for (int c = 0; c < 16; ++c)
    q += ws[OFF_PARTQ + ((size_t)(m*16 + c)*4 + b)*256 + d];
  ws[(m ? OFF_QA : OFF_QE) + (size_t)b*D + d] = q;
  ws[(m ? QCA : QCE) + (size_t)b*D + d] = q + bias[3*D + d] + bias[0*D + d];
  red[d] = q * (bias[2*D + d] + bias[0*D + d]);
  __syncthreads();
  for (int s = 128; s > 0; s >>= 1) { if (d < s) red[d] += red[d+s]; __syncthreads(); }
  if (d == 0) ws[(m ? CAc : CEc) + b] = red[0];
  if (m == 1 && b == 0) {
    __syncthreads();
    red[d] = cskb[d] * a[D + d];
    __syncthreads();
    for (int s = 128; s > 0; s >>= 1) { if (d < s) red[d] += red[d+s]; __syncthreads(); }
    if (d == 0) ws[C2c] = 2.0f * red[0];
  }
}

// --- R2: 17 row-major matvecs, wave-per-row, coalesced -------------------------
__global__ __launch_bounds__(256) void k_rowdots(
    const float* __restrict__ eW, const float* __restrict__ aW,
    const float* __restrict__ cskW, const float* __restrict__ a,
    float* __restrict__ ws)
{
  int job = blockIdx.y;
  int wid = threadIdx.x >> 6, lane = threadIdx.x & 63;
  int row = blockIdx.x*4 + wid;
  __shared__ float vec[D];
  const float* M; size_t outo;
  if (job < 16) {
    int b = job >> 2, m = (job >> 1) & 1, which = job & 1;
    const float* base = m ? aW : eW;
    M = base + (which ? 0 : (size_t)2*D*D);          // wW : kW
    if (threadIdx.x < D)
      vec[threadIdx.x] = ws[(m ? OFF_QA : OFF_QE) + (size_t)b*D + threadIdx.x];
    outo = (which ? (m ? WQA : WQE) : (m ? KQA : KQE)) + (size_t)b*D;
  } else {
    M = cskW;
    if (threadIdx.x < D) vec[threadIdx.x] = a[D + threadIdx.x];
    outo = CA2;
  }
  __syncthreads();
  float4 w = *reinterpret_cast<const float4*>(&M[(size_t)row*D + lane*4]);
  float s = w.x*vec[lane*4] + w.y*vec[lane*4+1] + w.z*vec[lane*4+2] + w.w*vec[lane*4+3];
  s = wave_sum(s);
  if (lane == 0) ws[outo + row] = s;
}

// --- R6: u = select + u.wq row dots (one wave == one row) ---------------------
__global__ __launch_bounds__(256) void k_u(
    const float* __restrict__ ei, const float* __restrict__ eo,
    const float* __restrict__ ai, const float* __restrict__ ao,
    const int* __restrict__ cl, const int* __restrict__ intra,
    float* __restrict__ ws)
{
  size_t g = (size_t)blockIdx.x*256 + threadIdx.x;
  size_t base = g << 2;
  int b = (int)(base >> 19);              // N*D = 2^19
  int n = (int)((base >> 8) & (N - 1));
  int d0 = (int)(base & (D - 1));
  int t = cl[b] - 1;
  float tm = (float)intra[(size_t)b*N*N + (size_t)t*N + n];
  float om = 1.0f - tm;
  float4 vei = *(const float4*)&ei[base];
  float4 veo = *(const float4*)&eo[base];
  float4 vai = *(const float4*)&ai[base];
  float4 vao = *(const float4*)&ao[base];
  float4 ue, ua;
  ue.x = tm*vei.x + om*veo.x; ue.y = tm*vei.y + om*veo.y;
  ue.z = tm*vei.z + om*veo.z; ue.w = tm*vei.w + om*veo.w;
  ua.x = tm*vai.x + om*vao.x; ua.y = tm*vai.y + om*vao.y;
  ua.z = tm*vai.z + om*vao.z; ua.w = tm*vai.w + om*vao.w;
  *(float4*)&ws[OFF_UE + base] = ue;
  *(float4*)&ws[OFF_UA + base] = ua;
  float4 wqe = *(const float4*)&ws[WQE + (size_t)b*D + d0];
  float4 wqa = *(const float4*)&ws[WQA + (size_t)b*D + d0];
  float se = ue.x*wqe.x + ue.y*wqe.y + ue.z*wqe.z + ue.w*wqe.w;
  float sa = ua.x*wqa.x + ua.y*wqa.y + ua.z*wqa.z + ua.w*wqa.w;
  se = wave_sum(se); sa = wave_sum(sa);
  if ((threadIdx.x & 63) == 0) {
    size_t row = base >> 8;
    ws[OFF_LEU + row] = se;
    ws[OFF_LAU + row] = sa;
  }
}

// --- s1 = h.a1 ; s2 = h.a2 + (bef+aft).ca2 + c2 -------------------------------
__global__ __launch_bounds__(256) void k_s12(
    const float* __restrict__ bef, const float* __restrict__ aft,
    const float* __restrict__ a, float* __restrict__ ws)
{
  int wid  = (int)(((size_t)blockIdx.x*256 + threadIdx.x) >> 6);
  int lane = threadIdx.x & 63;
  int d0 = lane << 2;
  float4 a1 = *(const float4*)&a[d0];
  float4 a2 = *(const float4*)&a[D + d0];
  float4 cv = *(const float4*)&ws[CA2 + d0];
  float c2  = ws[C2c];
  for (int rr = 0; rr < 4; ++rr) {
    int row = wid*4 + rr;
    float4 h4 = *(const float4*)&ws[OFF_H + (size_t)row*D + d0];
    float4 b4 = *(const float4*)&bef[(size_t)row*D + d0];
    float4 f4 = *(const float4*)&aft[(size_t)row*D + d0];
    float s1 = h4.x*a1.x + h4.y*a1.y + h4.z*a1.z + h4.w*a1.w;
    float s2 = h4.x*a2.x + h4.y*a2.y + h4.z*a2.z + h4.w*a2.w
             + (b4.x+f4.x)*cv.x + (b4.y+f4.y)*cv.y
             + (b4.z+f4.z)*cv.z + (b4.w+f4.w)*cv.w;
    s1 = wave_sum(s1); s2 = wave_sum(s2);
    if (lane == 0) { ws[OFF_S1 + row] = s1; ws[OFF_S2 + row] = s2 + c2; }
  }
}

// --- R5: partial rank counts over 128-value k-chunks ---------------------------
__global__ __launch_bounds__(256) void k_cnt2(float* __restrict__ ws)
{
  int jb = blockIdx.x;          // 0..7
  int kb = blockIdx.y;          // 0..15
  int b  = blockIdx.z;
  int tid = threadIdx.x;
  __shared__ float ck[128];
  if (tid < 32)
    *(float4*)&ck[tid*4] = *(const float4*)&ws[OFF_S2 + (size_t)b*N + kb*128 + tid*4];
  __syncthreads();
  int j = jb*256 + tid;
  float v = ws[OFF_S2 + (size_t)b*N + j];
  int kg = kb*128;
  int cnt = 0;
#pragma unroll
  for (int k = 0; k < 128; k += 16) {
    float4 u0 = *(const float4*)&ck[k];
    float4 u1 = *(const float4*)&ck[k+4];
    float4 u2 = *(const float4*)&ck[k+8];
    float4 u3 = *(const float4*)&ck[k+12];
    cnt += (u0.x < v) || (u0.x == v && (kg+k+ 0) < j);
    cnt += (u0.y < v) || (u0.y == v && (kg+k+ 1) < j);
    cnt += (u0.z < v) || (u0.z == v && (kg+k+ 2) < j);
    cnt += (u0.w < v) || (u0.w == v && (kg+k+ 3) < j);
    cnt += (u1.x < v) || (u1.x == v && (kg+k+ 4) < j);
    cnt += (u1.y < v) || (u1.y == v && (kg+k+ 5) < j);
    cnt += (u1.z < v) || (u1.z == v && (kg+k+ 6) < j);
    cnt += (u1.w < v) || (u1.w == v && (kg+k+ 7) < j);
    cnt += (u2.x < v) || (u2.x == v && (kg+k+ 8) < j);
    cnt += (u2.y < v) || (u2.y == v && (kg+k+ 9) < j);
    cnt += (u2.z < v) || (u2.z == v && (kg+k+10) < j);
    cnt += (u2.w < v) || (u2.w == v && (kg+k+11) < j);
    cnt += (u3.x < v) || (u3.x == v && (kg+k+12) < j);
    cnt += (u3.y < v) || (u3.y == v && (kg+k+13) < j);
    cnt += (u3.z < v) || (u3.z == v && (kg+k+14) < j);
    cnt += (u3.w < v) || (u3.w == v && (kg+k+15) < j);
  }
  ((int*)ws)[OFF_PCNT + ((size_t)(b*16 + kb))*N + j] = cnt;
}

// --- R5: sum partial counts, scatter sorted SV/SIDX/WP/WN ----------------------
__global__ __launch_bounds__(256) void k_cntfin(float* __restrict__ ws)
{
  int b = blockIdx.y;
  int j = blockIdx.x*256 + threadIdx.x;
  int cnt = 0;
#pragma unroll
  for (int kb = 0; kb < 16; ++kb)
    cnt += ((const int*)ws)[OFF_PCNT + ((size_t)(b*16 + kb))*N + j];
  float v = ws[OFF_S2 + (size_t)b*N + j];
  size_t o = (size_t)b*N + cnt;
  ws[OFF_SV + o] = v;
  ((int*)ws)[OFF_SIDX + o] = j;
  ws[OFF_WP + o] = expf(v);
  ws[OFF_WN + o] = expf(ALPHA*v);
}

// --- R4: scalar prefix sums of sorted WP/WN -> ZP/ZN ---------------------------
__global__ __launch_bounds__(1024) void k_scan(float* __restrict__ ws)
{
  int b = blockIdx.x, m = blockIdx.y, t = threadIdx.x;
  const float* src = ws + (m ? OFF_WN : OFF_WP) + (size_t)b*N;
  float* dst = ws + (m ? OFF_ZN : OFF_ZP) + (size_t)b*(N+1);
  __shared__ float buf[N];
  buf[t] = src[t]; buf[t + 1024] = src[t + 1024];
  __syncthreads();
  for (int off = 1; off < N; off <<= 1) {
    float v0 = (t >= off)        ? buf[t - off]        : 0.f;
    float v1 = (t + 1024 >= off) ? buf[t + 1024 - off] : 0.f;
    __syncthreads();
    buf[t] += v0; buf[t + 1024] += v1;
    __syncthreads();
  }
  if (t == 0) dst[0] = 0.f;
  dst[t + 1]    = buf[t];
  dst[t + 1025] = buf[t + 1024];
}

// --- R1: per-row rank + folded softmax coefficients ----------------------------
__global__ __launch_bounds__(256) void k_rank(float* __restrict__ ws)
{
  int b = blockIdx.y;
  int i = blockIdx.x * 256 + threadIdx.x;
  __shared__ float sv[N];
  for (int r = threadIdx.x; r < N; r += 256) sv[r] = ws[OFF_SV + (size_t)b*N + r];
  __syncthreads();
  float s1i = ws[OFF_S1 + (size_t)b*N + i];
  float th = -s1i;
  int lo = 0, hi = N;
  while (lo < hi) { int mid = (lo + hi) >> 1; if (sv[mid] <= th) lo = mid + 1; else hi = mid; }
  int r = lo;
  float ep = expf(s1i), en = expf(ALPHA*s1i);
  float zp  = ws[OFF_ZP + (size_t)b*(N+1) + r];
  float zn  = ws[OFF_ZN + (size_t)b*(N+1) + r];
  float zpT = ws[OFF_ZP + (size_t)b*(N+1) + N];
  float den = ep*(zpT - zp) + en*zn;
  ((int*)ws)[OFF_RNK + (size_t)b*N + i] = r;
  ws[OFF_C0 + (size_t)b*N + i] = ep/den;
  ws[OFF_C1 + (size_t)b*N + i] = en/den;
}

// --- vector partials over sorted order ----------------------------------------
__global__ __launch_bounds__(256) void k_p1(float* __restrict__ ws)
{
  int c = blockIdx.x, b = blockIdx.y, d = threadIdx.x;
  const int*   sidx = (const int*)ws + OFF_SIDX + (size_t)b*N;
  const float* wp = ws + OFF_WP + (size_t)b*N;
  const float* wn = ws + OFF_WN + (size_t)b*N;
  const float* h  = ws + OFF_H + (size_t)b*N*D;
  float ap = 0.f, an = 0.f;
  for (int r = c*64; r < c*64 + 64; ++r) {
    float hv = h[(size_t)sidx[r]*D + d];
    ap += wp[r]*hv; an += wn[r]*hv;
  }
  ws[OFF_PARTP + ((size_t)b*32 + c)*D + d] = ap;
  ws[OFF_PARTN + ((size_t)b*32 + c)*D + d] = an;
}

// --- R4: p3 computes its own chunk offset --------------------------------------
__global__ __launch_bounds__(256) void k_p3(float* __restrict__ ws)
{
  int c = blockIdx.x, b = blockIdx.y, d = threadIdx.x;
  const int*   sidx = (const int*)ws + OFF_SIDX + (size_t)b*N;
  const float* wp = ws + OFF_WP + (size_t)b*N;
  const float* wn = ws + OFF_WN + (size_t)b*N;
  const float* h  = ws + OFF_H + (size_t)b*N*D;
  float ap = 0.f, an = 0.f;
  for (int c2 = 0; c2 < c; ++c2) {
    ap += ws[OFF_PARTP + ((size_t)b*32 + c2)*D + d];
    an += ws[OFF_PARTN + ((size_t)b*32 + c2)*D + d];
  }
  for (int r = c*64; r < c*64 + 64; ++r) {
    ws[OFF_PPOS + ((size_t)b*(N+1) + r)*D + d] = ap;
    ws[OFF_PNEG + ((size_t)b*(N+1) + r)*D + d] = an;
    float hv = h[(size_t)sidx[r]*D + d];
    ap += wp[r]*hv; an += wn[r]*hv;
  }
  if (c == 31) {
    ws[OFF_PPOS + ((size_t)b*(N+1) + N)*D + d] = ap;
    ws[OFF_PNEG + ((size_t)b*(N+1) + N)*D + d] = an;
  }
}

// --- R6: h_prime gather + hp-part of logits (u-part comes from LEU/LAU) -------
__global__ __launch_bounds__(256) void k_hprime2(float* __restrict__ ws)
{
  int b = blockIdx.y, d = threadIdx.x;
  int i0 = blockIdx.x * 8;
  float totp = ws[OFF_PPOS + ((size_t)b*(N+1) + N)*D + d];
  float kqe = ws[KQE + (size_t)b*D + d];
  float kqa = ws[KQA + (size_t)b*D + d];
  float se[8], sa[8];
#pragma unroll
  for (int ii = 0; ii < 8; ++ii) {
    int i = i0 + ii;
    int   r  = ((const int*)ws)[OFF_RNK + (size_t)b*N + i];
    float c0 = ws[OFF_C0 + (size_t)b*N + i];
    float c1 = ws[OFF_C1 + (size_t)b*N + i];
    float pp = ws[OFF_PPOS + ((size_t)b*(N+1) + r)*D + d];
    float pn = ws[OFF_PNEG + ((size_t)b*(N+1) + r)*D + d];
    float v = c0*(totp - pp) + c1*pn;
    ws[OFF_HP + ((size_t)b*N + i)*D + d] = v;
    se[ii] = v*kqe;
    sa[ii] = v*kqa;
  }
  __shared__ float lred[16][4];
  int w = d >> 6, lane = d & 63;
#pragma unroll
  for (int ii = 0; ii < 8; ++ii) {
    float s = wave_sum(se[ii]);
    if (lane == 0) lred[ii][w] = s;
    s = wave_sum(sa[ii]);
    if (lane == 0) lred[8 + ii][w] = s;
  }
  __syncthreads();
  if (d < 16) {
    float s = lred[d][0] + lred[d][1] + lred[d][2] + lred[d][3];
    size_t row = (size_t)b*N + i0 + (d & 7);
    if (d < 8) ws[OFF_LE + row] = (s + ws[OFF_LEU + row] + ws[CEc + b]) * INVS;
    else       ws[OFF_LA + row] = (s + ws[OFF_LAU + row] + ws[CAc + b]) * INVS;
  }
}

// --- R6: per-(b,measure) softmax max + inv-sum ---------------------------------
__global__ __launch_bounds__(256) void k_smred(float* __restrict__ ws)
{
  int b = blockIdx.x, m = blockIdx.y, t = threadIdx.x;
  const float* l = ws + (m ? OFF_LA : OFF_LE) + (size_t)b*N;
  __shared__ float red[256];
  float v[8];
  float mx = -1e30f;
#pragma unroll
  for (int k = 0; k < 8; ++k) { v[k] = l[t*8 + k]; mx = fmaxf(mx, v[k]); }
  red[t] = mx; __syncthreads();
  for (int s = 128; s > 0; s >>= 1) { if (t < s) red[t] = fmaxf(red[t], red[t+s]); __syncthreads(); }
  mx = red[0]; __syncthreads();
  float sum = 0.f;
#pragma unroll
  for (int k = 0; k < 8; ++k) sum += expf(v[k] - mx);
  red[t] = sum; __syncthreads();
  for (int s = 128; s > 0; s >>= 1) { if (t < s) red[t] += red[t+s]; __syncthreads(); }
  if (t == 0) {
    ws[(m ? SMXA : SMXE) + b] = mx;
    ws[(m ? SIVA : SIVE) + b] = 1.0f / red[0];
  }
}

// --- R7: fused tail, BM=32/BN=128, grid (256,2) = 512 blocks, 4 waves ---------
// Wave tile 32x32: acc[meas][i][j] (8 f32x4 = 32 VGPR). Both measures per block.
// Epilogue: probs (y==0 blocks) + out = relu(hp+inp+pe*(qce+Ve)+pa*(qca+Va)).
__global__ __launch_bounds__(256) void k_tail(
    const float* __restrict__ inp, const ushort* __restrict__ bt,
    float* __restrict__ ws, float* __restrict__ out)
{
  __shared__ ushort Hs[32*40], Es[32*40], Zs[32*40];
  __shared__ float qec[256], qac[256];
  const int t = threadIdx.x;
  const int m0 = blockIdx.x * 32, n0 = blockIdx.y * 128;
  const int b = m0 >> 11;
  const int lane = t & 63, w = t >> 6;               // w = wave col-quarter
  const int laneN = lane & 15, kg = lane >> 4;
  qec[t] = ws[QCE + (size_t)b*D + t];
  qac[t] = ws[QCA + (size_t)b*D + t];
  const int srow = t >> 3, sc = (t & 7) * 4;
  const float* hp = ws + OFF_HP;
  const float* ue = ws + OFF_UE;
  const float* ua = ws + OFF_UA;
  const ushort* Bve = bt + 1*65536;
  const ushort* Bwe = bt + 2*65536;
  const ushort* Bva = bt + 3*65536;
  const ushort* Bwa = bt + 4*65536;
  f32x4 accE[2][2] = {}, accA[2][2] = {};
  for (int k0 = 0; k0 < 256; k0 += 32) {
    __syncthreads();
    size_t abase = (size_t)(m0 + srow)*256 + k0 + sc;
    float4 h4 = *(const float4*)&hp[abase];
    float4 e4 = *(const float4*)&ue[abase];
    float4 z4 = *(const float4*)&ua[abase];
    uint2 oh; oh.x = pk2bf(h4.x, h4.y); oh.y = pk2bf(h4.z, h4.w);
    uint2 oe; oe.x = pk2bf(e4.x, e4.y); oe.y = pk2bf(e4.z, e4.w);
    uint2 oz; oz.x = pk2bf(z4.x, z4.y); oz.y = pk2bf(z4.z, z4.w);
    *(uint2*)&Hs[srow*40 + sc] = oh;
    *(uint2*)&Es[srow*40 + sc] = oe;
    *(uint2*)&Zs[srow*40 + sc] = oz;
    __syncthreads();
    bf16x8 hf[2], ef[2], zf[2];
#pragma unroll
    for (int i = 0; i < 2; ++i) {
      hf[i] = *(const bf16x8*)&Hs[(i*16 + laneN)*40 + kg*8];
      ef[i] = *(const bf16x8*)&Es[(i*16 + laneN)*40 + kg*8];
      zf[i] = *(const bf16x8*)&Zs[(i*16 + laneN)*40 + kg*8];
    }
#pragma unroll
    for (int j = 0; j < 2; ++j) {
      size_t cb = (size_t)(n0 + w*32 + j*16 + laneN)*256 + k0 + kg*8;
      bf16x8 bve = *(const bf16x8*)&Bve[cb];
      bf16x8 bwe = *(const bf16x8*)&Bwe[cb];
      bf16x8 bva = *(const bf16x8*)&Bva[cb];
      bf16x8 bwa = *(const bf16x8*)&Bwa[cb];
#pragma unroll
      for (int i = 0; i < 2; ++i) {
        accE[i][j] = __builtin_amdgcn_mfma_f32_16x16x32_bf16(hf[i], bve, accE[i][j], 0, 0, 0);
        accE[i][j] = __builtin_amdgcn_mfma_f32_16x16x32_bf16(ef[i], bwe, accE[i][j], 0, 0, 0);
        accA[i][j] = __builtin_amdgcn_mfma_f32_16x16x32_bf16(hf[i], bva, accA[i][j], 0, 0, 0);
        accA[i][j] = __builtin_amdgcn_mfma_f32_16x16x32_bf16(zf[i], bwa, accA[i][j], 0, 0, 0);
      }
    }
  }
  float smxe = ws[SMXE + b], sive = ws[SIVE + b];
  float smxa = ws[SMXA + b], siva = ws[SIVA + b];
  if (blockIdx.y == 0 && t < 32) {
    size_t row = (size_t)m0 + t;
    int n = (int)(row & (N - 1));
    float pe = expf(ws[OFF_LE + row] - smxe) * sive;
    float pa = expf(ws[OFF_LA + row] - smxa) * siva;
    out[(size_t)B*N*D + (size_t)b*N + n] = pe;
    out[(size_t)B*N*D + (size_t)B*N + (size_t)b*N + n] = pa;
  }
#pragma unroll
  for (int i = 0; i < 2; ++i) {
#pragma unroll
    for (int r = 0; r < 4; ++r) {
      size_t row = (size_t)m0 + i*16 + kg*4 + r;
      float pe = expf(ws[OFF_LE + row] - smxe) * sive;
      float pa = expf(ws[OFF_LA + row] - smxa) * siva;
#pragma unroll
      for (int j = 0; j < 2; ++j) {
        int col = n0 + w*32 + j*16 + laneN;
        size_t idx = row*256 + col;
        float o = hp[idx] + inp[idx] + pe*(qec[col] + accE[i][j][r]) + pa*(qac[col] + accA[i][j][r]);
        out[idx] = fmaxf(o, 0.f);
      }
    }
  }
}

extern "C" void kernel_launch(void* const* d_in, const int* in_sizes, int n_in,
                              void* d_out, int out_size, void* d_ws, size_t ws_size,
                              hipStream_t stream) {
  const float* inp  = (const float*)d_in[0];
  const float* emo  = (const float*)d_in[1];
  const float* bef  = (const float*)d_in[2];
  const float* aft  = (const float*)d_in[3];
  const float* ei   = (const float*)d_in[4];
  const float* eo   = (const float*)d_in[5];
  const float* ii   = (const float*)d_in[6];
  const float* io   = (const float*)d_in[7];
  const float* W    = (const float*)d_in[8];
  const float* a    = (const float*)d_in[9];
  const float* cskW = (const float*)d_in[10];
  const float* cskb = (const float*)d_in[11];
  const float* eW   = (const float*)d_in[12];
  const float* eb   = (const float*)d_in[13];
  const float* aW   = (const float*)d_in[14];
  const float* ab   = (const float*)d_in[15];
  const int*   cl   = (const int*)d_in[16];
  const int*   intra= (const int*)d_in[17];
  float* ws  = (float*)d_ws;
  float* out = (float*)d_out;
  ushort* bt = (ushort*)(ws + OFF_BT);

  k_btq<<<dim3(16, 7), 256, 0, stream>>>(W, eW, aW, inp, emo, cl, bt, ws);
  k_mgemmh<<<dim3(256, 2), 256, 0, stream>>>(inp, bt, ws + OFF_H);
  k_qfinish<<<dim3(B, 2), 256, 0, stream>>>(eb, ab, cskb, a, ws);
  k_rowdots<<<dim3(64, 17), 256, 0, stream>>>(eW, aW, cskW, a, ws);
  k_u<<<2048, 256, 0, stream>>>(ei, eo, ii, io, cl, intra, ws);
  k_s12<<<512, 256, 0, stream>>>(bef, aft, a, ws);
  k_cnt2<<<dim3(8, 16, B), 256, 0, stream>>>(ws);
  k_cntfin<<<dim3(8, B), 256, 0, stream>>>(ws);
  k_scan<<<dim3(B, 2), 1024, 0, stream>>>(ws);
  k_rank<<<dim3(8, B), 256, 0, stream>>>(ws);
  k_p1<<<dim3(32, B), 256, 0, stream>>>(ws);
  k_p3<<<dim3(32, B), 256, 0, stream>>>(ws);
  k_hprime2<<<dim3(256, B), 256, 0, stream>>>(ws);
  k_smred<<<dim3(B, 2), 256, 0, stream>>>(ws);
  k_tail<<<dim3(256, 2), 256, 0, stream>>>(inp, bt, ws, out);
}